// Round 17
// baseline (512.541 us; speedup 1.0000x reference)
//
#include <hip/hip_runtime.h>
#include <stdint.h>

// ---------------------------------------------------------------------------
// MT_Attention fused pipeline, round 17:
//  - QK moved back into gemm_bt<MODE_QK,1,64>: 32KB LDS (5 blocks/CU vs
//    gemm_qk's 64KB / 2 blocks/CU), 2 lockstep K-steps, band-skip + masked
//    store preserved (code from r6/r8, validated).
//  - everything else identical to round 16 (506 µs best).
// ---------------------------------------------------------------------------

#define H_   32
#define D_   128
#define HID_ 4096
#define WMAX2 944
#define LPAD 8

typedef unsigned short bfr;  // raw bf16 bits
typedef __attribute__((ext_vector_type(4))) float f32x4;
typedef __attribute__((ext_vector_type(4))) int   i32x4;
typedef __attribute__((ext_vector_type(8))) unsigned short u16x8;
typedef __attribute__((ext_vector_type(4))) unsigned short u16x4;

__device__ __forceinline__ bfr f2bf(float f) {
  uint32_t u = __float_as_uint(f);
  u += 0x7fffu + ((u >> 16) & 1u);   // RNE
  return (bfr)(u >> 16);
}
__device__ __forceinline__ float bf2f(bfr u) {
  return __uint_as_float(((uint32_t)u) << 16);
}
__device__ __forceinline__ void mfma_bf16(f32x4& d, i32x4 a, i32x4 b) {
  asm volatile("v_mfma_f32_16x16x32_bf16 %0, %1, %2, %0" : "+v"(d) : "v"(a), "v"(b));
}
__device__ __forceinline__ void gload_lds16(const void* g, void* l) {
  __builtin_amdgcn_global_load_lds((__attribute__((address_space(1))) void*)g,
                                   (__attribute__((address_space(3))) void*)l,
                                   16, 0, 0);
}

// ---------------------------------------------------------------------------
// Segment setup.
// ---------------------------------------------------------------------------
__global__ __launch_bounds__(256) void seg_setup(
    const void* __restrict__ qsl, const void* __restrict__ ksl,
    int* __restrict__ segq, int* __restrict__ segk,
    int* __restrict__ bq, int* __restrict__ bk,
    float* __restrict__ stats, int S, int Sk, int nseg)
{
  __shared__ int sbq[16], sbk[16];
  const int tid = threadIdx.x;
  if (tid == 0) {
    {
      const int* q32 = (const int*)qsl;
      long long s32 = 0; bool ok32 = true;
      for (int i = 0; i < nseg; ++i) { int v = q32[i]; if (v < 1 || v > S) ok32 = false; s32 += v; }
      const bool use32 = ok32 && (s32 == S);
      const long long* q64 = (const long long*)qsl;
      sbq[0] = 0;
      for (int i = 0; i < nseg; ++i) sbq[i + 1] = sbq[i] + (use32 ? q32[i] : (int)q64[i]);
    }
    {
      const int* k32 = (const int*)ksl;
      long long s32 = 0; bool ok32 = true;
      for (int i = 0; i < nseg; ++i) { int v = k32[i]; if (v < 1 || v > Sk) ok32 = false; s32 += v; }
      const bool use32 = ok32 && (s32 == Sk);
      const long long* k64 = (const long long*)ksl;
      sbk[0] = 0;
      for (int i = 0; i < nseg; ++i) sbk[i + 1] = sbk[i] + (use32 ? k32[i] : (int)k64[i]);
    }
    for (int i = 0; i <= nseg; ++i) { bq[i] = sbq[i]; bk[i] = sbk[i]; }
  }
  if (tid < 32) stats[tid] = 0.f;
  __syncthreads();
  for (int i = tid; i < S; i += 256) {
    int s = 0;
    while (s < nseg - 1 && i >= sbq[s + 1]) ++s;
    segq[i] = s;
  }
  for (int i = tid; i < Sk; i += 256) {
    int s = 0;
    while (s < nseg - 1 && i >= sbk[s + 1]) ++s;
    segk[i] = s;
  }
}

// ---------------------------------------------------------------------------
// Elementwise f32 -> bf16.
// ---------------------------------------------------------------------------
__global__ __launch_bounds__(256) void cvt_bf16(
    const float* __restrict__ in, bfr* __restrict__ out, long long n)
{
  long long i = ((long long)blockIdx.x * 256 + threadIdx.x) * 8;
  if (i >= n) return;
  f32x4 a = *(const f32x4*)(in + i);
  f32x4 b = *(const f32x4*)(in + i + 4);
  u16x8 o;
  #pragma unroll
  for (int j = 0; j < 4; ++j) { o[j] = f2bf(a[j]); o[4 + j] = f2bf(b[j]); }
  *(u16x8*)(out + i) = o;
}

// ---------------------------------------------------------------------------
// Tiled transpose + f32->bf16, source row stride ld.
// ---------------------------------------------------------------------------
__global__ __launch_bounds__(256) void transpose_cvt(
    const float* __restrict__ in, bfr* __restrict__ out, int R, int ld)
{
  __shared__ float tile[64][65];
  const int t = threadIdx.x;
  const int rb = blockIdx.y * 64, cb = blockIdx.x * 64;
  const int row = t >> 2, c4 = (t & 3) * 16;
  const float* gp = in + (long long)(rb + row) * ld + cb + c4;
  #pragma unroll
  for (int j = 0; j < 4; ++j) {
    f32x4 v = *(const f32x4*)(gp + j * 4);
    #pragma unroll
    for (int q = 0; q < 4; ++q) tile[row][c4 + j * 4 + q] = v[q];
  }
  __syncthreads();
  const int cc = row, r4 = c4;
  u16x8 a, b;
  #pragma unroll
  for (int j = 0; j < 8; ++j) a[j] = f2bf(tile[r4 + j][cc]);
  #pragma unroll
  for (int j = 0; j < 8; ++j) b[j] = f2bf(tile[r4 + 8 + j][cc]);
  bfr* op = out + (long long)(cb + cc) * R + rb + r4;
  *(u16x8*)op = a;
  *(u16x8*)(op + 8) = b;
}

// ---------------------------------------------------------------------------
// Per-head bf16 transpose: in [R][C] -> out [C][R], z = head.
// ---------------------------------------------------------------------------
__global__ __launch_bounds__(256) void transpose_b16(
    const bfr* __restrict__ in, bfr* __restrict__ out, int R, int C)
{
  __shared__ bfr t[64][72];
  const int z = blockIdx.z;
  const bfr* ip = in + (long long)z * R * C;
  bfr* op = out + (long long)z * R * C;
  const int rb = blockIdx.y * 64, cb = blockIdx.x * 64;
  const int tr = threadIdx.x >> 3;
  const int tc = (threadIdx.x & 7) * 8;
  #pragma unroll
  for (int half = 0; half < 2; ++half) {
    const int r = tr + half * 32;
    u16x8 v = *(const u16x8*)(ip + (long long)(rb + r) * C + cb + tc);
    *(u16x8*)&t[r][tc] = v;
  }
  __syncthreads();
  #pragma unroll
  for (int half = 0; half < 2; ++half) {
    const int cc = tr + half * 32;
    u16x8 vv;
    #pragma unroll
    for (int j = 0; j < 8; ++j) vv[j] = t[tc + j][cc];
    *(u16x8*)(op + (long long)(cb + cc) * R + rb + tc) = vv;
  }
}

// ---------------------------------------------------------------------------
// Column sums of V^T rows.
// ---------------------------------------------------------------------------
__global__ __launch_bounds__(256) void colsum_v(
    const bfr* __restrict__ vt, float* __restrict__ cs, int Sk)
{
  const int lane = threadIdx.x & 63, wave = threadIdx.x >> 6;
  const int row = blockIdx.x * 4 + wave;
  const bfr* src = vt + (long long)row * Sk;
  float s = 0.f;
  for (int i = lane * 8; i + 8 <= Sk; i += 512) {
    u16x8 v = *(const u16x8*)(src + i);
    #pragma unroll
    for (int j = 0; j < 8; ++j) s += bf2f(v[j]);
  }
  #pragma unroll
  for (int m = 1; m < 64; m <<= 1) s += __shfl_xor(s, m);
  if (lane == 0) cs[row] = s;
}

// ---------------------------------------------------------------------------
struct GemmAux {
  const int* segq; const int* segk; const int* bk;
  bfr* qb; bfr* kb; bfr* vrow;
  float* outb;          // split-K f32 partials
  bfr* outb16;          // PV bf16 output
  float* stats;
  const float* fvArr; const float* colsum;
  float scale;
  int S, Sk, nOff;
};

enum { MODE_PLAIN = 0, MODE_Q = 1, MODE_KV = 2, MODE_QK = 3, MODE_PV = 4 };

// ---------------------------------------------------------------------------
// 4-wave BT GEMM, 128x128 tile, single-buffer lockstep loop, zero-conflict
// XOR swizzle. BKL = K-step (32 or 64). KS>1 = split-K (z = slice).
// MODE_QK: band tile-skip, zero-fill outside mask, masked bf16 store.
// ---------------------------------------------------------------------------
template <int MODE, int KS = 1, int BKL = 32>
__global__ __launch_bounds__(256) void gemm_bt(
    const bfr* __restrict__ A, const bfr* __restrict__ Bt, void* __restrict__ Cout,
    int N, int K, int lda, int ldb,
    long long aZ, long long bZ, long long cZ, GemmAux aux)
{
  __shared__ bfr As[128 * BKL];
  __shared__ bfr Bs[128 * BKL];
  __shared__ float redS[8], redSS[8];
  const int tid = threadIdx.x;
  const int lane = tid & 63;
  const int wave = tid >> 6;
  const int z = blockIdx.z;

  int bx = blockIdx.x, by = blockIdx.y;
  {
    const int gx = gridDim.x, gy = gridDim.y;
    if (((gx & 3) == 0) && ((gy & 1) == 0)) {
      const int lid = by * gx + bx;
      const int xcd = lid & 7, inner = lid >> 3;
      const int cm = gy >> 1, cn = gx >> 2;
      by = (xcd >> 2) * cm + inner / cn;
      bx = (xcd & 3) * cn + inner % cn;
    }
  }
  const int m0 = by * 128;
  const int n0 = bx * 128;
  const bfr* Ap = A + (long long)z * aZ;
  const bfr* Bp = Bt + (long long)z * bZ;

  if constexpr (MODE == MODE_QK) {
    // tiles beyond the conv read band (+16 margin) are never read: skip
    const int t127 = min(m0 + 127, aux.S - 1);
    const int loT = max(aux.bk[aux.segq[max(m0 - 2, 0)]] - 4, 0);
    const int hiT = min(aux.bk[aux.segq[min(t127 + 1, aux.S - 1)] + 1] + 4, aux.Sk);
    if (n0 > hiT + 16 || n0 + 127 < loT - 16) return;
    // near-band but fully outside block-diagonal mask: zero-fill
    const int sm0 = aux.segq[m0], sm1 = aux.segq[t127];
    const int sn0 = aux.segk[n0], sn1 = aux.segk[min(n0 + 127, aux.Sk - 1)];
    if (sm1 < sn0 || sn1 < sm0) {
      bfr* C = (bfr*)Cout + (long long)z * cZ + (long long)m0 * aux.Sk + n0;
      const i32x4 zz = {0, 0, 0, 0};
      #pragma unroll
      for (int c = 0; c < 8; ++c) {
        int id = c * 256 + tid;
        int r = id >> 4, col = (id & 15) * 8;
        *(i32x4*)(C + (long long)r * aux.Sk + col) = zz;
      }
      return;
    }
  }

  int kLo = 0, kHiV = K;
  if constexpr (KS > 1) { const int ksp = K / KS; kLo = z * ksp; kHiV = kLo + ksp; }
  if constexpr (MODE == MODE_PV) {
    const int t127 = min(m0 + 127, aux.S - 1);
    kLo = (max(aux.bk[aux.segq[max(m0 - 2, 0)]] - 4, 0)) & ~31;
    int th = min(aux.bk[aux.segq[min(t127 + 1, aux.S - 1)] + 1] + 4, aux.Sk);
    kHiV = min((th + 31) & ~31, aux.Sk);
  }

  const int wr = (wave >> 1) * 64;
  const int wc = (wave & 1) * 64;
  f32x4 acc[4][4];
  #pragma unroll
  for (int i = 0; i < 4; ++i)
    #pragma unroll
    for (int j = 0; j < 4; ++j) acc[i][j] = (f32x4){0.f, 0.f, 0.f, 0.f};

  // BK=32 swizzle (64B rows, 4 slots): key (R>>1)&3. Verified r9/r10: 0 conflicts.
  const int srow32 = lane >> 2;
  const int scol32 = (((lane & 3) ^ ((lane >> 3) & 3)) << 3);
  const int rcol32 = (((lane >> 4) ^ ((lane >> 1) & 3)) << 3);
  // BK=64 swizzle (128B rows, 8 slots of 16B): key row&7. Verified r11: 0 conflicts.
  const int srow64 = lane >> 3;
  const int scol64 = (((lane & 7) ^ ((lane >> 3) & 7)) << 3);

  const int kSteps = (kHiV - kLo) >> (BKL == 32 ? 5 : 6);
  for (int ks = 0; ks < kSteps; ++ks) {
    const int k0 = kLo + ks * BKL;
    if constexpr (BKL == 32) {
      #pragma unroll
      for (int c = 0; c < 4; ++c) {
        const int chunk = (wave << 2) + c;
        const int ci = chunk & 7;
        const int row = ci * 16 + srow32;
        if (chunk < 8) gload_lds16(Ap + (long long)(m0 + row) * lda + k0 + scol32, As + ci * 512);
        else           gload_lds16(Bp + (long long)(n0 + row) * ldb + k0 + scol32, Bs + ci * 512);
      }
    } else {
      #pragma unroll
      for (int c = 0; c < 8; ++c) {
        const int chunk = wave * 8 + c;           // 0..31: 16 A + 16 B chunks (1KB each)
        const int ci = chunk & 15;
        const int row = ci * 8 + srow64;
        if (chunk < 16) gload_lds16(Ap + (long long)(m0 + row) * lda + k0 + scol64, As + ci * 512);
        else            gload_lds16(Bp + (long long)(n0 + row) * ldb + k0 + scol64, Bs + ci * 512);
      }
    }
    __syncthreads();   // lockstep: keeps co-resident blocks' K-phases aligned (L2)
    if constexpr (BKL == 32) {
      i32x4 af[4], bfv[4];
      #pragma unroll
      for (int i = 0; i < 4; ++i)
        af[i] = *(const i32x4*)&As[(wr + i * 16 + (lane & 15)) * 32 + rcol32];
      #pragma unroll
      for (int i = 0; i < 4; ++i)
        bfv[i] = *(const i32x4*)&Bs[(wc + i * 16 + (lane & 15)) * 32 + rcol32];
      #pragma unroll
      for (int i = 0; i < 4; ++i)
        #pragma unroll
        for (int j = 0; j < 4; ++j)
          mfma_bf16(acc[i][j], af[i], bfv[j]);
    } else {
      #pragma unroll
      for (int ks2 = 0; ks2 < 2; ++ks2) {
        const int rcol = (((ks2 * 4 + (lane >> 4)) ^ (lane & 7)) << 3);
        i32x4 af[4], bfv[4];
        #pragma unroll
        for (int i = 0; i < 4; ++i)
          af[i] = *(const i32x4*)&As[(wr + i * 16 + (lane & 15)) * 64 + rcol];
        #pragma unroll
        for (int i = 0; i < 4; ++i)
          bfv[i] = *(const i32x4*)&Bs[(wc + i * 16 + (lane & 15)) * 64 + rcol];
        #pragma unroll
        for (int i = 0; i < 4; ++i)
          #pragma unroll
          for (int j = 0; j < 4; ++j)
            mfma_bf16(acc[i][j], af[i], bfv[j]);
      }
    }
    __syncthreads();
  }

  // epilogue hoists
  bool qkUni = false;
  int sgm[16], sgn[4];
  float fvm[16], csn[4];
  if constexpr (MODE == MODE_QK) {
    const int sA = aux.segq[m0], sB = aux.segq[min(m0 + 127, aux.S - 1)];
    const int sC = aux.segk[n0], sD = aux.segk[min(n0 + 127, aux.Sk - 1)];
    qkUni = (sA == sB) && (sC == sD);
    if (!qkUni) {
      #pragma unroll
      for (int i = 0; i < 4; ++i)
        #pragma unroll
        for (int r = 0; r < 4; ++r)
          sgm[i * 4 + r] = aux.segq[m0 + wr + i * 16 + (lane >> 4) * 4 + r];
      #pragma unroll
      for (int j = 0; j < 4; ++j) sgn[j] = aux.segk[n0 + wc + j * 16 + (lane & 15)];
    }
  }
  if constexpr (MODE == MODE_PV) {
    #pragma unroll
    for (int i = 0; i < 4; ++i)
      #pragma unroll
      for (int r = 0; r < 4; ++r)
        fvm[i * 4 + r] = aux.fvArr[(long long)z * aux.S + m0 + wr + i * 16 + (lane >> 4) * 4 + r];
    #pragma unroll
    for (int j = 0; j < 4; ++j)
      csn[j] = aux.colsum[(long long)z * D_ + n0 + wc + j * 16 + (lane & 15)];
  }

  float sv = 0.f, sq2 = 0.f;
  #pragma unroll
  for (int i = 0; i < 4; ++i) {
    #pragma unroll
    for (int j = 0; j < 4; ++j) {
      #pragma unroll
      for (int r = 0; r < 4; ++r) {
        const int m = m0 + wr + i * 16 + (lane >> 4) * 4 + r;
        const int n = n0 + wc + j * 16 + (lane & 15);
        const float v = acc[i][j][r];
        if constexpr (KS > 1) {
          aux.outb[((long long)z * aux.S + m) * N + n] = v;   // f32 partial
        } else if constexpr (MODE == MODE_PLAIN) {
          ((float*)Cout)[(long long)m * N + n] = v;
        } else if constexpr (MODE == MODE_Q) {
          const int hh = n >> 7, d = n & 127;
          aux.qb[((long long)hh * aux.S + m) * D_ + d] = f2bf(v * aux.scale);
        } else if constexpr (MODE == MODE_KV) {
          const int ng = n + aux.nOff;
          if (ng < H_ * D_) {
            const int hh = ng >> 7, d = ng & 127;
            aux.kb[((long long)hh * aux.Sk + m) * D_ + d] = f2bf(v);
          } else {
            const int nv = ng - H_ * D_;
            const int hh = nv >> 7, d = nv & 127;
            aux.vrow[((long long)hh * aux.Sk + m) * D_ + d] = f2bf(v);
          }
        } else if constexpr (MODE == MODE_QK) {
          const float vv = (qkUni || sgm[i * 4 + r] == sgn[j]) ? v : 0.f;
          ((bfr*)Cout)[(long long)z * cZ + (long long)m * aux.Sk + n] = f2bf(vv);
        } else if constexpr (MODE == MODE_PV) {
          const float vv = v + fvm[i * 4 + r] * csn[j];
          aux.outb16[((long long)z * aux.S + m) * D_ + n] = f2bf(vv);
          sv += vv; sq2 += vv * vv;
        }
      }
    }
  }

  if constexpr (MODE == MODE_PV && KS == 1) {
    #pragma unroll
    for (int msk = 1; msk < 64; msk <<= 1) {
      sv  += __shfl_xor(sv, msk);
      sq2 += __shfl_xor(sq2, msk);
    }
    if (lane == 0) { redS[wave] = sv; redSS[wave] = sq2; }
    __syncthreads();
    if (tid == 0) {
      const float a = redS[0] + redS[1] + redS[2] + redS[3];
      const float b = redSS[0] + redSS[1] + redSS[2] + redSS[3];
      atomicAdd(&aux.stats[(z >> 1) * 2 + 0], a);
      atomicAdd(&aux.stats[(z >> 1) * 2 + 1], b);
    }
  }
}

// ---------------------------------------------------------------------------
// Split-K reduces.
// ---------------------------------------------------------------------------
__global__ __launch_bounds__(256) void reduce_split_q(
    const float* __restrict__ part, bfr* __restrict__ qb, float scale, int S)
{
  const long long MN = (long long)S * HID_;
  const long long i = ((long long)blockIdx.x * 256 + threadIdx.x) * 8;
  if (i >= MN) return;
  const f32x4 a0 = *(const f32x4*)(part + i);
  const f32x4 a1 = *(const f32x4*)(part + i + 4);
  const f32x4 b0 = *(const f32x4*)(part + MN + i);
  const f32x4 b1 = *(const f32x4*)(part + MN + i + 4);
  const int m = (int)(i >> 12);
  const int n = (int)(i & 4095);
  const int hh = n >> 7, d = n & 127;
  u16x8 o;
  #pragma unroll
  for (int j = 0; j < 4; ++j) {
    o[j]     = f2bf((a0[j] + b0[j]) * scale);
    o[4 + j] = f2bf((a1[j] + b1[j]) * scale);
  }
  *(u16x8*)(qb + ((long long)hh * S + m) * D_ + d) = o;
}

__global__ __launch_bounds__(256) void reduce_split_f32(
    const float* __restrict__ part, float* __restrict__ out, long long MN)
{
  const long long i = ((long long)blockIdx.x * 256 + threadIdx.x) * 8;
  if (i >= MN) return;
  const f32x4 a0 = *(const f32x4*)(part + i);
  const f32x4 a1 = *(const f32x4*)(part + i + 4);
  const f32x4 b0 = *(const f32x4*)(part + MN + i);
  const f32x4 b1 = *(const f32x4*)(part + MN + i + 4);
  f32x4 o0, o1;
  #pragma unroll
  for (int j = 0; j < 4; ++j) { o0[j] = a0[j] + b0[j]; o1[j] = a1[j] + b1[j]; }
  *(f32x4*)(out + i) = o0;
  *(f32x4*)(out + i + 4) = o1;
}

// ---------------------------------------------------------------------------
// Banded conv(4x9) + softmax, head-pair, 256 thr, 4 q-rows/block, 8 out/lane.
// ---------------------------------------------------------------------------
__global__ __launch_bounds__(256) void conv_softmax9(
    const bfr* __restrict__ attn, const float* __restrict__ conv_w,
    bfr* __restrict__ p, float* __restrict__ fvArr,
    const int* __restrict__ segq, const int* __restrict__ segk,
    const int* __restrict__ bk, int S, int Sk, int h0)
{
  __shared__ float wsh[144];
  __shared__ bfr sIn[7][WMAX2];
  const int tid = threadIdx.x, lane = tid & 63, w = tid >> 6;
  const int q0 = blockIdx.x * 4;
  const int c0 = blockIdx.y * 2;
  const int h  = h0 + c0;
  if (tid < 144) wsh[tid] = conv_w[h * 72 + tid];

  const int lo0 = (max(bk[segq[max(q0 - 2, 0)]] - 4, 0)) & ~7;
  const int hiL = min(bk[segq[min(q0 + 4, S - 1)] + 1] + 4, Sk);
  const int g0 = max(lo0 - 8, 0) & ~7;
  const int g1 = min(hiL + 4, Sk);
  const int W8 = (g1 - g0 + 7) >> 3;

  const int qa = q0 + w;
  const int loA = (max(bk[segq[max(qa - 2, 0)]] - 4, 0)) & ~7;
  const int hiA = min(bk[segq[min(qa + 1, S - 1)] + 1] + 4, Sk);
  const int sqA = segq[qa];
  const int width = hiA - loA;

  float lg[2][2][8];
  #pragma unroll
  for (int e = 0; e < 2; ++e)
    #pragma unroll
    for (int pp = 0; pp < 2; ++pp)
      #pragma unroll
      for (int o = 0; o < 8; ++o) lg[e][pp][o] = 0.f;

  if (tid < 7) {
    const u16x8 zz8 = {0,0,0,0,0,0,0,0};
    *(u16x8*)&sIn[tid][0] = zz8;
    *(u16x8*)&sIn[tid][LPAD + W8 * 8] = zz8;
  }

  for (int pass = 0; pass < 2; ++pass) {
    if (pass) __syncthreads();
    const bfr* src0 = attn + (long long)(c0 + pass) * S * Sk;
    for (int it = tid; it < 7 * 116; it += 256) {
      const int ri = it / 116;
      const int j  = it - ri * 116;
      if (j < W8) {
        const int r = q0 - 2 + ri;
        u16x8 v = {0,0,0,0,0,0,0,0};
        if (r >= 0 && r < S) v = *(const u16x8*)(src0 + (long long)r * Sk + g0 + j * 8);
        *(u16x8*)&sIn[ri][LPAD + j * 8] = v;
      }
    }
    __syncthreads();

    #pragma unroll
    for (int pp = 0; pp < 2; ++pp) {
      const int kk = loA + pp * 512 + lane * 8;
      if (kk < hiA) {
        const int ib2 = LPAD + kk - 8 - g0;   // 16B-aligned
        #pragma unroll
        for (int rr = 0; rr < 4; ++rr) {
          const bfr* sp = &sIn[w + rr][ib2];
          u16x8 u0 = *(const u16x8*)(sp);
          u16x8 u1 = *(const u16x8*)(sp + 8);
          u16x8 u2 = *(const u16x8*)(sp + 16);
          float xx[16];                         // xx[i] = pos kk-4+i
          #pragma unroll
          for (int j2 = 0; j2 < 4; ++j2) {
            xx[j2]      = bf2f(u0[4 + j2]);
            xx[4 + j2]  = bf2f(u1[j2]);
            xx[8 + j2]  = bf2f(u1[4 + j2]);
            xx[12 + j2] = bf2f(u2[j2]);
          }
          const float* wv0 = &wsh[(pass * 4 + rr) * 9];
          const float* wv1 = wv0 + 72;
          #pragma unroll
          for (int dk = 0; dk < 9; ++dk) {
            #pragma unroll
            for (int o = 0; o < 8; ++o) {
              lg[0][pp][o] += xx[o + dk] * wv0[dk];
              lg[1][pp][o] += xx[o + dk] * wv1[dk];
            }
          }
        }
      }
    }
  }

  float lmax0 = -1e30f, lmax1 = -1e30f;
  #pragma unroll
  for (int pp = 0; pp < 2; ++pp) {
    const int kk = loA + pp * 512 + lane * 8;
    int sk8[8];
    if (kk < Sk) {
      i32x4 a = *(const i32x4*)&segk[kk];
      i32x4 b = *(const i32x4*)&segk[kk + 4];
      #pragma unroll
      for (int j = 0; j < 4; ++j) { sk8[j] = a[j]; sk8[4 + j] = b[j]; }
    } else {
      #pragma unroll
      for (int j = 0; j < 8; ++j) sk8[j] = -1;
    }
    #pragma unroll
    for (int o = 0; o < 8; ++o) {
      const int k = kk + o;
      float v0 = -1e30f, v1 = -1e30f;
      if (k < hiA) {
        const float mb = (sk8[o] == sqA) ? 1.f : 0.f;
        v0 = lg[0][pp][o] + mb; lmax0 = fmaxf(lmax0, v0);
        v1 = lg[1][pp][o] + mb; lmax1 = fmaxf(lmax1, v1);
      }
      lg[0][pp][o] = v0; lg[1][pp][o] = v1;
    }
  }
  #pragma unroll
  for (int m = 1; m < 64; m <<= 1) {
    lmax0 = fmaxf(lmax0, __shfl_xor(lmax0, m));
    lmax1 = fmaxf(lmax1, __shfl_xor(lmax1, m));
  }
  const float M0 = fmaxf(lmax0, 0.f), M1 = fmaxf(lmax1, 0.f);
  float ls0 = 0.f, ls1 = 0.f;
  #pragma unroll
  for (int pp = 0; pp < 2; ++pp)
    #pragma unroll
    for (int o = 0; o < 8; ++o) {
      const float e0 = __expf(lg[0][pp][o] - M0);
      const float e1 = __expf(lg[1][pp][o] - M1);
      lg[0][pp][o] = e0; ls0 += e0;
      lg[1][pp][o] = e1; ls1 += e1;
    }
  #pragma unroll
  for (int m = 1; m < 64; m <<= 1) {
    ls0 += __shfl_xor(ls0, m);
    ls1 += __shfl_xor(ls1, m);
  }
  const float eo0 = __expf(-M0), eo1 = __expf(-M1);
  const float iv0 = 1.f / (ls0 + (float)(Sk - width) * eo0);
  const float iv1 = 1.f / (ls1 + (float)(Sk - width) * eo1);
  const float fv0 = eo0 * iv0, fv1 = eo1 * iv1;

  const int t0 = (q0 >> 7) << 7;
  const int t127 = min(t0 + 127, S - 1);
  const int tLo = (max(bk[segq[max(t0 - 2, 0)]] - 4, 0)) & ~31;
  int tHi = min(bk[segq[min(t127 + 1, S - 1)] + 1] + 4, Sk);
  tHi = min((tHi + 31) & ~31, Sk);

  bfr* row0 = p + ((long long)(c0 + 0) * S + qa) * Sk;
  bfr* row1 = p + ((long long)(c0 + 1) * S + qa) * Sk;
  #pragma unroll
  for (int pp = 0; pp < 2; ++pp) {
    const int kk = loA + pp * 512 + lane * 8;
    if (kk + 7 < hiA) {
      u16x8 s0, s1;
      #pragma unroll
      for (int o = 0; o < 8; ++o) {
        s0[o] = f2bf(lg[0][pp][o] * iv0 - fv0);
        s1[o] = f2bf(lg[1][pp][o] * iv1 - fv1);
      }
      *(u16x8*)(row0 + kk) = s0;
      *(u16x8*)(row1 + kk) = s1;
    } else if (kk < hiA) {
      for (int o = 0; o < 8; ++o)
        if (kk + o < hiA) {
          row0[kk + o] = f2bf(lg[0][pp][o] * iv0 - fv0);
          row1[kk + o] = f2bf(lg[1][pp][o] * iv1 - fv1);
        }
    }
  }
  const u16x4 z4 = {0, 0, 0, 0};
  for (int k = tLo + lane * 4; k < loA; k += 256) {
    *(u16x4*)(row0 + k) = z4;
    *(u16x4*)(row1 + k) = z4;
  }
  for (int k = hiA + lane; k < tHi; k += 64) { row0[k] = 0; row1[k] = 0; }
  if (lane == 0) {
    fvArr[(long long)(h + 0) * S + qa] = fv0;
    fvArr[(long long)(h + 1) * S + qa] = fv1;
  }
}

// ---------------------------------------------------------------------------
// GroupNorm finalize + apply (reads bf16 outb).
// ---------------------------------------------------------------------------
__global__ void gn_finalize(const float* __restrict__ stats, float* __restrict__ mr, float invcnt)
{
  const int g = threadIdx.x;
  if (g < 16) {
    const float s = stats[2 * g], ss = stats[2 * g + 1];
    const float mu = s * invcnt;
    const float var = ss * invcnt - mu * mu;
    mr[2 * g] = mu;
    mr[2 * g + 1] = rsqrtf(var + 1e-5f);
  }
}

__global__ __launch_bounds__(256) void gn_apply(
    const bfr* __restrict__ outb, const float* __restrict__ mr,
    const float* __restrict__ gnw, const float* __restrict__ gnb,
    bfr* __restrict__ y, int S)
{
  const int h = blockIdx.y;
  const long long inner = ((long long)blockIdx.x * 256 + threadIdx.x) * 8;
  if (inner >= (long long)S * D_) return;
  const int s = (int)(inner >> 7), d = (int)(inner & 127);
  const int g = h >> 1;
  const float mu = mr[2 * g], rs = mr[2 * g + 1];
  const float wgt = gnw[h] * rs;
  const float b = gnb[h] - mu * wgt;
  const u16x8 v = *(const u16x8*)(outb + (long long)h * S * D_ + inner);
  u16x8 o;
  #pragma unroll
  for (int j = 0; j < 8; ++j) o[j] = f2bf(bf2f(v[j]) * wgt + b);
  *(u16x8*)(y + (long long)s * HID_ + h * D_ + d) = o;
}

// ---------------------------------------------------------------------------
// Launcher.
// ---------------------------------------------------------------------------
extern "C" void kernel_launch(void* const* d_in, const int* in_sizes, int n_in,
                              void* d_out, int out_size, void* d_ws, size_t ws_size,
                              hipStream_t stream)
{
  const float* x      = (const float*)d_in[0];
  const float* ctx    = (const float*)d_in[1];
  const float* wq     = (const float*)d_in[2];
  const float* wkv    = (const float*)d_in[3];
  const float* wo     = (const float*)d_in[4];
  const float* conv_w = (const float*)d_in[5];
  const float* gnw    = (const float*)d_in[6];
  const float* gnb    = (const float*)d_in[7];
  const void*  qsl    = d_in[8];
  const void*  ksl    = d_in[9];
  const int S    = in_sizes[0] / HID_;   // 1536
  const int Sk   = in_sizes[1] / HID_;   // 1536
  const int nseg = in_sizes[8];          // 4

  auto al = [](size_t v) { return (v + 255) & ~(size_t)255; };
  char* base = (char*)d_ws;
  size_t off = 0;
  auto take = [&](size_t bytes) -> char* { char* r = base + off; off += al(bytes); return r; };

  int*   segq  = (int*)take((size_t)S * 4);
  int*   segk  = (int*)take((size_t)Sk * 4);
  int*   bq    = (int*)take(64);
  int*   bk    = (int*)take(64);
  float* stats = (float*)take(128);
  float* mr    = (float*)take(128);
  float* fvArr = (float*)take((size_t)H_ * S * 4);
  float* csV   = (float*)take((size_t)H_ * D_ * 4);
  bfr*   qb    = (bfr*)take((size_t)H_ * S * D_ * 2);
  bfr*   kbuf  = (bfr*)take((size_t)H_ * Sk * D_ * 2);
  bfr*   vrow  = (bfr*)take((size_t)H_ * Sk * D_ * 2);
  bfr*   vt    = (bfr*)take((size_t)H_ * Sk * D_ * 2);
  bfr*   outb  = (bfr*)take((size_t)H_ * S * D_ * 2);   // bf16
  const size_t poolBase = off;
  char*  pool  = base + poolBase;

  const int Smax = (S > Sk) ? S : Sk;
  const size_t A1 = al((size_t)Smax * HID_ * 2);
  const size_t WT = al((size_t)HID_ * HID_ * 2);
  const size_t PART = al((size_t)2 * S * HID_ * 4);

  const size_t CAmin = al((size_t)4 * S * Sk * 2);
  const size_t fusedNeed = (A1 + 2 * WT > 2 * CAmin) ? (A1 + 2 * WT) : (2 * CAmin);
  const bool fused = (poolBase + fusedNeed <= ws_size);
  const bool splitOK = (poolBase + A1 + 2 * WT + PART <= ws_size);
  const size_t wNeed = A1 + (fused ? 2 : 1) * WT + (splitOK ? PART : 0);

  int nc = 4;
  {
    const int cands[3] = {32, 16, 8};
    for (int ci = 0; ci < 3; ++ci) {
      const size_t CA = al((size_t)cands[ci] * S * Sk * 2);
      const size_t need = (wNeed > 2 * CA) ? wNeed : (2 * CA);
      if (poolBase + need <= ws_size) { nc = cands[ci]; break; }
    }
  }
  const size_t CA = al((size_t)nc * S * Sk * 2);
  bfr*   xcb    = (bfr*)pool;
  bfr*   wT     = (bfr*)(pool + A1);
  float* partB  = (float*)(pool + A1 + 2 * WT);
  bfr*   attn_c = (bfr*)pool;
  bfr*   pbuf_c = (bfr*)(pool + CA);

  seg_setup<<<1, 256, 0, stream>>>(qsl, ksl, segq, segk, bq, bk, stats, S, Sk, nseg);

  GemmAux aux{};
  aux.segq = segq; aux.segk = segk; aux.bk = bk;
  aux.qb = qb; aux.kb = kbuf; aux.vrow = vrow;
  aux.outb = nullptr; aux.outb16 = outb; aux.stats = stats;
  aux.fvArr = fvArr; aux.colsum = csV;
  aux.scale = 0.08838834764831845f;  // 1/sqrt(128)
  aux.S = S; aux.Sk = Sk; aux.nOff = 0;

  const long long MN = (long long)S * HID_;
  const int nRed = (int)((MN / 8 + 255) / 256);

  // ---- Q projection ----
  const long long nx = (long long)S * HID_;
  cvt_bf16<<<(int)((nx / 8 + 255) / 256), 256, 0, stream>>>(x, xcb, nx);
  transpose_cvt<<<dim3(HID_ / 64, HID_ / 64), 256, 0, stream>>>(wq, wT, HID_, HID_);
  if (splitOK) {
    GemmAux auxQ = aux; auxQ.outb = partB;
    gemm_bt<MODE_Q, 2, 64><<<dim3(HID_ / 128, S / 128, 2), 256, 0, stream>>>(
        xcb, wT, nullptr, HID_, HID_, HID_, HID_, 0, 0, 0, auxQ);
    reduce_split_q<<<nRed, 256, 0, stream>>>(partB, qb, aux.scale, S);
  } else {
    gemm_bt<MODE_Q, 1, 64><<<dim3(HID_ / 128, S / 128, 1), 256, 0, stream>>>(
        xcb, wT, nullptr, HID_, HID_, HID_, HID_, 0, 0, 0, aux);
  }

  // ---- KV projection ----
  const long long nctx = (long long)Sk * HID_;
  cvt_bf16<<<(int)((nctx / 8 + 255) / 256), 256, 0, stream>>>(ctx, xcb, nctx);
  if (fused) {
    transpose_cvt<<<dim3(2 * HID_ / 64, HID_ / 64), 256, 0, stream>>>(wkv, wT, HID_, 2 * HID_);
    gemm_bt<MODE_KV, 1, 64><<<dim3(2 * HID_ / 128, Sk / 128, 1), 256, 0, stream>>>(
        xcb, wT, nullptr, 2 * HID_, HID_, HID_, HID_, 0, 0, 0, aux);
  } else {
    transpose_cvt<<<dim3(HID_ / 64, HID_ / 64), 256, 0, stream>>>(wkv, wT, HID_, 2 * HID_);
    gemm_bt<MODE_KV, 1, 64><<<dim3(HID_ / 128, Sk / 128, 1), 256, 0, stream>>>(
        xcb, wT, nullptr, HID_, HID_, HID_, HID_, 0, 0, 0, aux);
    transpose_cvt<<<dim3(HID_ / 64, HID_ / 64), 256, 0, stream>>>(wkv + HID_, wT, HID_, 2 * HID_);
    GemmAux auxV = aux; auxV.nOff = H_ * D_;
    gemm_bt<MODE_KV, 1, 64><<<dim3(HID_ / 128, Sk / 128, 1), 256, 0, stream>>>(
        xcb, wT, nullptr, HID_, HID_, HID_, HID_, 0, 0, 0, auxV);
  }

  // ---- V transpose + column sums ----
  transpose_b16<<<dim3(D_ / 64, Sk / 64, H_), 256, 0, stream>>>(vrow, vt, Sk, D_);
  colsum_v<<<H_ * D_ / 4, 256, 0, stream>>>(vt, csV, Sk);

  // ---- attention, chunked over heads ----
  for (int h0 = 0; h0 < H_; h0 += nc) {
    gemm_bt<MODE_QK, 1, 64><<<dim3(Sk / 128, S / 128, nc), 256, 0, stream>>>(
        qb + (size_t)h0 * S * D_, kbuf + (size_t)h0 * Sk * D_, attn_c,
        Sk, D_, D_, D_,
        (long long)S * D_, (long long)Sk * D_, (long long)S * Sk, aux);
    conv_softmax9<<<dim3(S / 4, nc / 2), 256, 0, stream>>>(
        attn_c, conv_w, pbuf_c, fvArr, segq, segk, bk, S, Sk, h0);
    GemmAux auxP = aux;
    auxP.outb16 = outb + (size_t)h0 * S * D_;
    auxP.stats = stats + h0;
    auxP.fvArr = fvArr + (size_t)h0 * S;
    auxP.colsum = csV + (size_t)h0 * D_;
    gemm_bt<MODE_PV, 1, 32><<<dim3(1, S / 128, nc), 256, 0, stream>>>(
        pbuf_c, vt + (size_t)h0 * D_ * Sk, nullptr,
        D_, Sk, Sk, Sk,
        (long long)S * Sk, (long long)D_ * Sk, 0, auxP);
  }

  // ---- GroupNorm + output projection ----
  gn_finalize<<<1, 32, 0, stream>>>(stats, mr, 1.0f / (2.0f * S * D_));
  gn_apply<<<dim3((S * D_) / 2048, H_), 256, 0, stream>>>(outb, mr, gnw, gnb, xcb, S);
  transpose_cvt<<<dim3(HID_ / 64, HID_ / 64), 256, 0, stream>>>(wo, wT, HID_, HID_);
  if (splitOK) {
    GemmAux auxO = aux; auxO.outb = partB;
    gemm_bt<MODE_PLAIN, 2, 64><<<dim3(HID_ / 128, S / 128, 2), 256, 0, stream>>>(
        xcb, wT, nullptr, HID_, HID_, HID_, HID_, 0, 0, 0, auxO);
    reduce_split_f32<<<nRed, 256, 0, stream>>>(partB, (float*)d_out, MN);
  } else {
    gemm_bt<MODE_PLAIN, 1, 64><<<dim3(HID_ / 128, S / 128, 1), 256, 0, stream>>>(
        xcb, wT, d_out, HID_, HID_, HID_, HID_, 0, 0, 0, aux);
  }
}

// Round 18
// 506.718 us; speedup vs baseline: 1.0115x; 1.0115x over previous
//
#include <hip/hip_runtime.h>
#include <stdint.h>

// ---------------------------------------------------------------------------
// MT_Attention fused pipeline, round 18 = round 16 (measured best, 506.2us):
//  - 4-wave BK=64 lockstep GEMMs (Q/KV/OUT) + zero-conflict XOR swizzles
//  - split-K=2 on Q/OUT with deterministic f32 partials
//  - gemm_qk: K=128 fully LDS-staged, one barrier (beats 2-step BK=64: r17)
//  - banded conv_softmax9 (256 thr / 4 q-rows), banded PV + fv*colsumV
//  - bf16 outb intermediate (PV -> GroupNorm)
// ---------------------------------------------------------------------------

#define H_   32
#define D_   128
#define HID_ 4096
#define WMAX2 944
#define LPAD 8

typedef unsigned short bfr;  // raw bf16 bits
typedef __attribute__((ext_vector_type(4))) float f32x4;
typedef __attribute__((ext_vector_type(4))) int   i32x4;
typedef __attribute__((ext_vector_type(8))) unsigned short u16x8;
typedef __attribute__((ext_vector_type(4))) unsigned short u16x4;

__device__ __forceinline__ bfr f2bf(float f) {
  uint32_t u = __float_as_uint(f);
  u += 0x7fffu + ((u >> 16) & 1u);   // RNE
  return (bfr)(u >> 16);
}
__device__ __forceinline__ float bf2f(bfr u) {
  return __uint_as_float(((uint32_t)u) << 16);
}
__device__ __forceinline__ void mfma_bf16(f32x4& d, i32x4 a, i32x4 b) {
  asm volatile("v_mfma_f32_16x16x32_bf16 %0, %1, %2, %0" : "+v"(d) : "v"(a), "v"(b));
}
__device__ __forceinline__ void gload_lds16(const void* g, void* l) {
  __builtin_amdgcn_global_load_lds((__attribute__((address_space(1))) void*)g,
                                   (__attribute__((address_space(3))) void*)l,
                                   16, 0, 0);
}

// ---------------------------------------------------------------------------
// Segment setup.
// ---------------------------------------------------------------------------
__global__ __launch_bounds__(256) void seg_setup(
    const void* __restrict__ qsl, const void* __restrict__ ksl,
    int* __restrict__ segq, int* __restrict__ segk,
    int* __restrict__ bq, int* __restrict__ bk,
    float* __restrict__ stats, int S, int Sk, int nseg)
{
  __shared__ int sbq[16], sbk[16];
  const int tid = threadIdx.x;
  if (tid == 0) {
    {
      const int* q32 = (const int*)qsl;
      long long s32 = 0; bool ok32 = true;
      for (int i = 0; i < nseg; ++i) { int v = q32[i]; if (v < 1 || v > S) ok32 = false; s32 += v; }
      const bool use32 = ok32 && (s32 == S);
      const long long* q64 = (const long long*)qsl;
      sbq[0] = 0;
      for (int i = 0; i < nseg; ++i) sbq[i + 1] = sbq[i] + (use32 ? q32[i] : (int)q64[i]);
    }
    {
      const int* k32 = (const int*)ksl;
      long long s32 = 0; bool ok32 = true;
      for (int i = 0; i < nseg; ++i) { int v = k32[i]; if (v < 1 || v > Sk) ok32 = false; s32 += v; }
      const bool use32 = ok32 && (s32 == Sk);
      const long long* k64 = (const long long*)ksl;
      sbk[0] = 0;
      for (int i = 0; i < nseg; ++i) sbk[i + 1] = sbk[i] + (use32 ? k32[i] : (int)k64[i]);
    }
    for (int i = 0; i <= nseg; ++i) { bq[i] = sbq[i]; bk[i] = sbk[i]; }
  }
  if (tid < 32) stats[tid] = 0.f;
  __syncthreads();
  for (int i = tid; i < S; i += 256) {
    int s = 0;
    while (s < nseg - 1 && i >= sbq[s + 1]) ++s;
    segq[i] = s;
  }
  for (int i = tid; i < Sk; i += 256) {
    int s = 0;
    while (s < nseg - 1 && i >= sbk[s + 1]) ++s;
    segk[i] = s;
  }
}

// ---------------------------------------------------------------------------
// Elementwise f32 -> bf16.
// ---------------------------------------------------------------------------
__global__ __launch_bounds__(256) void cvt_bf16(
    const float* __restrict__ in, bfr* __restrict__ out, long long n)
{
  long long i = ((long long)blockIdx.x * 256 + threadIdx.x) * 8;
  if (i >= n) return;
  f32x4 a = *(const f32x4*)(in + i);
  f32x4 b = *(const f32x4*)(in + i + 4);
  u16x8 o;
  #pragma unroll
  for (int j = 0; j < 4; ++j) { o[j] = f2bf(a[j]); o[4 + j] = f2bf(b[j]); }
  *(u16x8*)(out + i) = o;
}

// ---------------------------------------------------------------------------
// Tiled transpose + f32->bf16, source row stride ld.
// ---------------------------------------------------------------------------
__global__ __launch_bounds__(256) void transpose_cvt(
    const float* __restrict__ in, bfr* __restrict__ out, int R, int ld)
{
  __shared__ float tile[64][65];
  const int t = threadIdx.x;
  const int rb = blockIdx.y * 64, cb = blockIdx.x * 64;
  const int row = t >> 2, c4 = (t & 3) * 16;
  const float* gp = in + (long long)(rb + row) * ld + cb + c4;
  #pragma unroll
  for (int j = 0; j < 4; ++j) {
    f32x4 v = *(const f32x4*)(gp + j * 4);
    #pragma unroll
    for (int q = 0; q < 4; ++q) tile[row][c4 + j * 4 + q] = v[q];
  }
  __syncthreads();
  const int cc = row, r4 = c4;
  u16x8 a, b;
  #pragma unroll
  for (int j = 0; j < 8; ++j) a[j] = f2bf(tile[r4 + j][cc]);
  #pragma unroll
  for (int j = 0; j < 8; ++j) b[j] = f2bf(tile[r4 + 8 + j][cc]);
  bfr* op = out + (long long)(cb + cc) * R + rb + r4;
  *(u16x8*)op = a;
  *(u16x8*)(op + 8) = b;
}

// ---------------------------------------------------------------------------
// Per-head bf16 transpose: in [R][C] -> out [C][R], z = head.
// ---------------------------------------------------------------------------
__global__ __launch_bounds__(256) void transpose_b16(
    const bfr* __restrict__ in, bfr* __restrict__ out, int R, int C)
{
  __shared__ bfr t[64][72];
  const int z = blockIdx.z;
  const bfr* ip = in + (long long)z * R * C;
  bfr* op = out + (long long)z * R * C;
  const int rb = blockIdx.y * 64, cb = blockIdx.x * 64;
  const int tr = threadIdx.x >> 3;
  const int tc = (threadIdx.x & 7) * 8;
  #pragma unroll
  for (int half = 0; half < 2; ++half) {
    const int r = tr + half * 32;
    u16x8 v = *(const u16x8*)(ip + (long long)(rb + r) * C + cb + tc);
    *(u16x8*)&t[r][tc] = v;
  }
  __syncthreads();
  #pragma unroll
  for (int half = 0; half < 2; ++half) {
    const int cc = tr + half * 32;
    u16x8 vv;
    #pragma unroll
    for (int j = 0; j < 8; ++j) vv[j] = t[tc + j][cc];
    *(u16x8*)(op + (long long)(cb + cc) * R + rb + tc) = vv;
  }
}

// ---------------------------------------------------------------------------
// Column sums of V^T rows.
// ---------------------------------------------------------------------------
__global__ __launch_bounds__(256) void colsum_v(
    const bfr* __restrict__ vt, float* __restrict__ cs, int Sk)
{
  const int lane = threadIdx.x & 63, wave = threadIdx.x >> 6;
  const int row = blockIdx.x * 4 + wave;
  const bfr* src = vt + (long long)row * Sk;
  float s = 0.f;
  for (int i = lane * 8; i + 8 <= Sk; i += 512) {
    u16x8 v = *(const u16x8*)(src + i);
    #pragma unroll
    for (int j = 0; j < 8; ++j) s += bf2f(v[j]);
  }
  #pragma unroll
  for (int m = 1; m < 64; m <<= 1) s += __shfl_xor(s, m);
  if (lane == 0) cs[row] = s;
}

// ---------------------------------------------------------------------------
struct GemmAux {
  const int* segq; const int* segk; const int* bk;
  bfr* qb; bfr* kb; bfr* vrow;
  float* outb;          // split-K f32 partials
  bfr* outb16;          // PV bf16 output
  float* stats;
  const float* fvArr; const float* colsum;
  float scale;
  int S, Sk, nOff;
};

enum { MODE_PLAIN = 0, MODE_Q = 1, MODE_KV = 2, MODE_QK = 3, MODE_PV = 4 };

// ---------------------------------------------------------------------------
// 4-wave BT GEMM, 128x128 tile, single-buffer lockstep loop, zero-conflict
// XOR swizzle. BKL = K-step (32 or 64). KS>1 = split-K (z = slice).
// ---------------------------------------------------------------------------
template <int MODE, int KS = 1, int BKL = 32>
__global__ __launch_bounds__(256) void gemm_bt(
    const bfr* __restrict__ A, const bfr* __restrict__ Bt, void* __restrict__ Cout,
    int N, int K, int lda, int ldb,
    long long aZ, long long bZ, long long cZ, GemmAux aux)
{
  __shared__ bfr As[128 * BKL];
  __shared__ bfr Bs[128 * BKL];
  __shared__ float redS[8], redSS[8];
  const int tid = threadIdx.x;
  const int lane = tid & 63;
  const int wave = tid >> 6;
  const int z = blockIdx.z;

  int bx = blockIdx.x, by = blockIdx.y;
  {
    const int gx = gridDim.x, gy = gridDim.y;
    if (((gx & 3) == 0) && ((gy & 1) == 0)) {
      const int lid = by * gx + bx;
      const int xcd = lid & 7, inner = lid >> 3;
      const int cm = gy >> 1, cn = gx >> 2;
      by = (xcd >> 2) * cm + inner / cn;
      bx = (xcd & 3) * cn + inner % cn;
    }
  }
  const int m0 = by * 128;
  const int n0 = bx * 128;
  const bfr* Ap = A + (long long)z * aZ;
  const bfr* Bp = Bt + (long long)z * bZ;

  int kLo = 0, kHiV = K;
  if constexpr (KS > 1) { const int ksp = K / KS; kLo = z * ksp; kHiV = kLo + ksp; }
  if constexpr (MODE == MODE_PV) {
    const int t127 = min(m0 + 127, aux.S - 1);
    kLo = (max(aux.bk[aux.segq[max(m0 - 2, 0)]] - 4, 0)) & ~31;
    int th = min(aux.bk[aux.segq[min(t127 + 1, aux.S - 1)] + 1] + 4, aux.Sk);
    kHiV = min((th + 31) & ~31, aux.Sk);
  }

  const int wr = (wave >> 1) * 64;
  const int wc = (wave & 1) * 64;
  f32x4 acc[4][4];
  #pragma unroll
  for (int i = 0; i < 4; ++i)
    #pragma unroll
    for (int j = 0; j < 4; ++j) acc[i][j] = (f32x4){0.f, 0.f, 0.f, 0.f};

  // BK=32 swizzle (64B rows, 4 slots): key (R>>1)&3. Verified r9/r10: 0 conflicts.
  const int srow32 = lane >> 2;
  const int scol32 = (((lane & 3) ^ ((lane >> 3) & 3)) << 3);
  const int rcol32 = (((lane >> 4) ^ ((lane >> 1) & 3)) << 3);
  // BK=64 swizzle (128B rows, 8 slots of 16B): key row&7. Verified r11: 0 conflicts.
  const int srow64 = lane >> 3;
  const int scol64 = (((lane & 7) ^ ((lane >> 3) & 7)) << 3);

  const int kSteps = (kHiV - kLo) >> (BKL == 32 ? 5 : 6);
  for (int ks = 0; ks < kSteps; ++ks) {
    const int k0 = kLo + ks * BKL;
    if constexpr (BKL == 32) {
      #pragma unroll
      for (int c = 0; c < 4; ++c) {
        const int chunk = (wave << 2) + c;
        const int ci = chunk & 7;
        const int row = ci * 16 + srow32;
        if (chunk < 8) gload_lds16(Ap + (long long)(m0 + row) * lda + k0 + scol32, As + ci * 512);
        else           gload_lds16(Bp + (long long)(n0 + row) * ldb + k0 + scol32, Bs + ci * 512);
      }
    } else {
      #pragma unroll
      for (int c = 0; c < 8; ++c) {
        const int chunk = wave * 8 + c;           // 0..31: 16 A + 16 B chunks (1KB each)
        const int ci = chunk & 15;
        const int row = ci * 8 + srow64;
        if (chunk < 16) gload_lds16(Ap + (long long)(m0 + row) * lda + k0 + scol64, As + ci * 512);
        else            gload_lds16(Bp + (long long)(n0 + row) * ldb + k0 + scol64, Bs + ci * 512);
      }
    }
    __syncthreads();   // lockstep: keeps co-resident blocks' K-phases aligned (L2)
    if constexpr (BKL == 32) {
      i32x4 af[4], bfv[4];
      #pragma unroll
      for (int i = 0; i < 4; ++i)
        af[i] = *(const i32x4*)&As[(wr + i * 16 + (lane & 15)) * 32 + rcol32];
      #pragma unroll
      for (int i = 0; i < 4; ++i)
        bfv[i] = *(const i32x4*)&Bs[(wc + i * 16 + (lane & 15)) * 32 + rcol32];
      #pragma unroll
      for (int i = 0; i < 4; ++i)
        #pragma unroll
        for (int j = 0; j < 4; ++j)
          mfma_bf16(acc[i][j], af[i], bfv[j]);
    } else {
      #pragma unroll
      for (int ks2 = 0; ks2 < 2; ++ks2) {
        const int rcol = (((ks2 * 4 + (lane >> 4)) ^ (lane & 7)) << 3);
        i32x4 af[4], bfv[4];
        #pragma unroll
        for (int i = 0; i < 4; ++i)
          af[i] = *(const i32x4*)&As[(wr + i * 16 + (lane & 15)) * 64 + rcol];
        #pragma unroll
        for (int i = 0; i < 4; ++i)
          bfv[i] = *(const i32x4*)&Bs[(wc + i * 16 + (lane & 15)) * 64 + rcol];
        #pragma unroll
        for (int i = 0; i < 4; ++i)
          #pragma unroll
          for (int j = 0; j < 4; ++j)
            mfma_bf16(acc[i][j], af[i], bfv[j]);
      }
    }
    __syncthreads();
  }

  float fvm[16], csn[4];
  if constexpr (MODE == MODE_PV) {
    #pragma unroll
    for (int i = 0; i < 4; ++i)
      #pragma unroll
      for (int r = 0; r < 4; ++r)
        fvm[i * 4 + r] = aux.fvArr[(long long)z * aux.S + m0 + wr + i * 16 + (lane >> 4) * 4 + r];
    #pragma unroll
    for (int j = 0; j < 4; ++j)
      csn[j] = aux.colsum[(long long)z * D_ + n0 + wc + j * 16 + (lane & 15)];
  }

  float sv = 0.f, sq2 = 0.f;
  #pragma unroll
  for (int i = 0; i < 4; ++i) {
    #pragma unroll
    for (int j = 0; j < 4; ++j) {
      #pragma unroll
      for (int r = 0; r < 4; ++r) {
        const int m = m0 + wr + i * 16 + (lane >> 4) * 4 + r;
        const int n = n0 + wc + j * 16 + (lane & 15);
        const float v = acc[i][j][r];
        if constexpr (KS > 1) {
          aux.outb[((long long)z * aux.S + m) * N + n] = v;   // f32 partial
        } else if constexpr (MODE == MODE_PLAIN) {
          ((float*)Cout)[(long long)m * N + n] = v;
        } else if constexpr (MODE == MODE_Q) {
          const int hh = n >> 7, d = n & 127;
          aux.qb[((long long)hh * aux.S + m) * D_ + d] = f2bf(v * aux.scale);
        } else if constexpr (MODE == MODE_KV) {
          const int ng = n + aux.nOff;
          if (ng < H_ * D_) {
            const int hh = ng >> 7, d = ng & 127;
            aux.kb[((long long)hh * aux.Sk + m) * D_ + d] = f2bf(v);
          } else {
            const int nv = ng - H_ * D_;
            const int hh = nv >> 7, d = nv & 127;
            aux.vrow[((long long)hh * aux.Sk + m) * D_ + d] = f2bf(v);
          }
        } else if constexpr (MODE == MODE_PV) {
          const float vv = v + fvm[i * 4 + r] * csn[j];
          aux.outb16[((long long)z * aux.S + m) * D_ + n] = f2bf(vv);
          sv += vv; sq2 += vv * vv;
        }
      }
    }
  }

  if constexpr (MODE == MODE_PV && KS == 1) {
    #pragma unroll
    for (int msk = 1; msk < 64; msk <<= 1) {
      sv  += __shfl_xor(sv, msk);
      sq2 += __shfl_xor(sq2, msk);
    }
    if (lane == 0) { redS[wave] = sv; redSS[wave] = sq2; }
    __syncthreads();
    if (tid == 0) {
      const float a = redS[0] + redS[1] + redS[2] + redS[3];
      const float b = redSS[0] + redSS[1] + redSS[2] + redSS[3];
      atomicAdd(&aux.stats[(z >> 1) * 2 + 0], a);
      atomicAdd(&aux.stats[(z >> 1) * 2 + 1], b);
    }
  }
}

// ---------------------------------------------------------------------------
// gemm_qk: K = D = 128 staged entirely in LDS, ONE barrier, 64 MFMA/wave.
// ---------------------------------------------------------------------------
__global__ __launch_bounds__(256) void gemm_qk(
    const bfr* __restrict__ A, const bfr* __restrict__ Bt, bfr* __restrict__ Cout,
    long long aZ, long long bZ, long long cZ, GemmAux aux)
{
  __shared__ bfr As[128 * 128];
  __shared__ bfr Bs[128 * 128];
  const int tid = threadIdx.x;
  const int lane = tid & 63;
  const int wave = tid >> 6;
  const int z = blockIdx.z;
  const int m0 = blockIdx.y * 128;
  const int n0 = blockIdx.x * 128;

  const int t127 = min(m0 + 127, aux.S - 1);
  const int loT = max(aux.bk[aux.segq[max(m0 - 2, 0)]] - 4, 0);
  const int hiT = min(aux.bk[aux.segq[min(t127 + 1, aux.S - 1)] + 1] + 4, aux.Sk);
  if (n0 > hiT + 16 || n0 + 127 < loT - 16) return;
  const int sm0 = aux.segq[m0], sm1 = aux.segq[t127];
  const int sn0 = aux.segk[n0], sn1 = aux.segk[min(n0 + 127, aux.Sk - 1)];
  if (sm1 < sn0 || sn1 < sm0) {
    bfr* C = Cout + (long long)z * cZ + (long long)m0 * aux.Sk + n0;
    const i32x4 zz = {0, 0, 0, 0};
    #pragma unroll
    for (int c = 0; c < 8; ++c) {
      int id = c * 256 + tid;
      int r = id >> 4, col = (id & 15) * 8;
      *(i32x4*)(C + (long long)r * aux.Sk + col) = zz;
    }
    return;
  }

  const bfr* Ap = A + (long long)z * aZ;
  const bfr* Bp = Bt + (long long)z * bZ;

  const int srow = lane >> 4;
  #pragma unroll
  for (int c = 0; c < 16; ++c) {
    const int chunk = wave * 16 + c;
    const int cl = chunk & 31;
    const int f = (2 * cl + (lane >> 5)) & 7;
    const int sc = ((lane & 15) ^ f) * 8;
    const int r = cl * 4 + srow;
    if (chunk < 32) gload_lds16(Ap + (long long)(m0 + r) * D_ + sc, As + cl * 512);
    else            gload_lds16(Bp + (long long)(n0 + r) * D_ + sc, Bs + cl * 512);
  }
  __syncthreads();

  const int wr = (wave >> 1) * 64;
  const int wc = (wave & 1) * 64;
  f32x4 acc[4][4];
  #pragma unroll
  for (int i = 0; i < 4; ++i)
    #pragma unroll
    for (int j = 0; j < 4; ++j) acc[i][j] = (f32x4){0.f, 0.f, 0.f, 0.f};

  const int rf = (lane >> 1) & 7;
  #pragma unroll
  for (int ks = 0; ks < 4; ++ks) {
    const int slot = (4 * ks + (lane >> 4)) ^ rf;
    const int colb = slot * 8;
    i32x4 af[4], bfv[4];
    #pragma unroll
    for (int i = 0; i < 4; ++i)
      af[i] = *(const i32x4*)&As[(wr + i * 16 + (lane & 15)) * 128 + colb];
    #pragma unroll
    for (int j = 0; j < 4; ++j)
      bfv[j] = *(const i32x4*)&Bs[(wc + j * 16 + (lane & 15)) * 128 + colb];
    #pragma unroll
    for (int i = 0; i < 4; ++i)
      #pragma unroll
      for (int j = 0; j < 4; ++j)
        mfma_bf16(acc[i][j], af[i], bfv[j]);
  }

  const bool qkUni = (sm0 == sm1) && (sn0 == sn1);
  int sgm[16], sgn[4];
  if (!qkUni) {
    #pragma unroll
    for (int i = 0; i < 4; ++i)
      #pragma unroll
      for (int r = 0; r < 4; ++r)
        sgm[i * 4 + r] = aux.segq[m0 + wr + i * 16 + (lane >> 4) * 4 + r];
    #pragma unroll
    for (int j = 0; j < 4; ++j) sgn[j] = aux.segk[n0 + wc + j * 16 + (lane & 15)];
  }
  #pragma unroll
  for (int i = 0; i < 4; ++i) {
    #pragma unroll
    for (int j = 0; j < 4; ++j) {
      #pragma unroll
      for (int r = 0; r < 4; ++r) {
        const int m = m0 + wr + i * 16 + (lane >> 4) * 4 + r;
        const int n = n0 + wc + j * 16 + (lane & 15);
        const float v = acc[i][j][r];
        const float vv = (qkUni || sgm[i * 4 + r] == sgn[j]) ? v : 0.f;
        Cout[(long long)z * cZ + (long long)m * aux.Sk + n] = f2bf(vv);
      }
    }
  }
}

// ---------------------------------------------------------------------------
// Split-K reduces.
// ---------------------------------------------------------------------------
__global__ __launch_bounds__(256) void reduce_split_q(
    const float* __restrict__ part, bfr* __restrict__ qb, float scale, int S)
{
  const long long MN = (long long)S * HID_;
  const long long i = ((long long)blockIdx.x * 256 + threadIdx.x) * 8;
  if (i >= MN) return;
  const f32x4 a0 = *(const f32x4*)(part + i);
  const f32x4 a1 = *(const f32x4*)(part + i + 4);
  const f32x4 b0 = *(const f32x4*)(part + MN + i);
  const f32x4 b1 = *(const f32x4*)(part + MN + i + 4);
  const int m = (int)(i >> 12);
  const int n = (int)(i & 4095);
  const int hh = n >> 7, d = n & 127;
  u16x8 o;
  #pragma unroll
  for (int j = 0; j < 4; ++j) {
    o[j]     = f2bf((a0[j] + b0[j]) * scale);
    o[4 + j] = f2bf((a1[j] + b1[j]) * scale);
  }
  *(u16x8*)(qb + ((long long)hh * S + m) * D_ + d) = o;
}

__global__ __launch_bounds__(256) void reduce_split_f32(
    const float* __restrict__ part, float* __restrict__ out, long long MN)
{
  const long long i = ((long long)blockIdx.x * 256 + threadIdx.x) * 8;
  if (i >= MN) return;
  const f32x4 a0 = *(const f32x4*)(part + i);
  const f32x4 a1 = *(const f32x4*)(part + i + 4);
  const f32x4 b0 = *(const f32x4*)(part + MN + i);
  const f32x4 b1 = *(const f32x4*)(part + MN + i + 4);
  f32x4 o0, o1;
  #pragma unroll
  for (int j = 0; j < 4; ++j) { o0[j] = a0[j] + b0[j]; o1[j] = a1[j] + b1[j]; }
  *(f32x4*)(out + i) = o0;
  *(f32x4*)(out + i + 4) = o1;
}

// ---------------------------------------------------------------------------
// Banded conv(4x9) + softmax, head-pair, 256 thr, 4 q-rows/block, 8 out/lane.
// ---------------------------------------------------------------------------
__global__ __launch_bounds__(256) void conv_softmax9(
    const bfr* __restrict__ attn, const float* __restrict__ conv_w,
    bfr* __restrict__ p, float* __restrict__ fvArr,
    const int* __restrict__ segq, const int* __restrict__ segk,
    const int* __restrict__ bk, int S, int Sk, int h0)
{
  __shared__ float wsh[144];
  __shared__ bfr sIn[7][WMAX2];
  const int tid = threadIdx.x, lane = tid & 63, w = tid >> 6;
  const int q0 = blockIdx.x * 4;
  const int c0 = blockIdx.y * 2;
  const int h  = h0 + c0;
  if (tid < 144) wsh[tid] = conv_w[h * 72 + tid];

  const int lo0 = (max(bk[segq[max(q0 - 2, 0)]] - 4, 0)) & ~7;
  const int hiL = min(bk[segq[min(q0 + 4, S - 1)] + 1] + 4, Sk);
  const int g0 = max(lo0 - 8, 0) & ~7;
  const int g1 = min(hiL + 4, Sk);
  const int W8 = (g1 - g0 + 7) >> 3;

  const int qa = q0 + w;
  const int loA = (max(bk[segq[max(qa - 2, 0)]] - 4, 0)) & ~7;
  const int hiA = min(bk[segq[min(qa + 1, S - 1)] + 1] + 4, Sk);
  const int sqA = segq[qa];
  const int width = hiA - loA;

  float lg[2][2][8];
  #pragma unroll
  for (int e = 0; e < 2; ++e)
    #pragma unroll
    for (int pp = 0; pp < 2; ++pp)
      #pragma unroll
      for (int o = 0; o < 8; ++o) lg[e][pp][o] = 0.f;

  if (tid < 7) {
    const u16x8 zz8 = {0,0,0,0,0,0,0,0};
    *(u16x8*)&sIn[tid][0] = zz8;
    *(u16x8*)&sIn[tid][LPAD + W8 * 8] = zz8;
  }

  for (int pass = 0; pass < 2; ++pass) {
    if (pass) __syncthreads();
    const bfr* src0 = attn + (long long)(c0 + pass) * S * Sk;
    for (int it = tid; it < 7 * 116; it += 256) {
      const int ri = it / 116;
      const int j  = it - ri * 116;
      if (j < W8) {
        const int r = q0 - 2 + ri;
        u16x8 v = {0,0,0,0,0,0,0,0};
        if (r >= 0 && r < S) v = *(const u16x8*)(src0 + (long long)r * Sk + g0 + j * 8);
        *(u16x8*)&sIn[ri][LPAD + j * 8] = v;
      }
    }
    __syncthreads();

    #pragma unroll
    for (int pp = 0; pp < 2; ++pp) {
      const int kk = loA + pp * 512 + lane * 8;
      if (kk < hiA) {
        const int ib2 = LPAD + kk - 8 - g0;   // 16B-aligned
        #pragma unroll
        for (int rr = 0; rr < 4; ++rr) {
          const bfr* sp = &sIn[w + rr][ib2];
          u16x8 u0 = *(const u16x8*)(sp);
          u16x8 u1 = *(const u16x8*)(sp + 8);
          u16x8 u2 = *(const u16x8*)(sp + 16);
          float xx[16];                         // xx[i] = pos kk-4+i
          #pragma unroll
          for (int j2 = 0; j2 < 4; ++j2) {
            xx[j2]      = bf2f(u0[4 + j2]);
            xx[4 + j2]  = bf2f(u1[j2]);
            xx[8 + j2]  = bf2f(u1[4 + j2]);
            xx[12 + j2] = bf2f(u2[j2]);
          }
          const float* wv0 = &wsh[(pass * 4 + rr) * 9];
          const float* wv1 = wv0 + 72;
          #pragma unroll
          for (int dk = 0; dk < 9; ++dk) {
            #pragma unroll
            for (int o = 0; o < 8; ++o) {
              lg[0][pp][o] += xx[o + dk] * wv0[dk];
              lg[1][pp][o] += xx[o + dk] * wv1[dk];
            }
          }
        }
      }
    }
  }

  float lmax0 = -1e30f, lmax1 = -1e30f;
  #pragma unroll
  for (int pp = 0; pp < 2; ++pp) {
    const int kk = loA + pp * 512 + lane * 8;
    int sk8[8];
    if (kk < Sk) {
      i32x4 a = *(const i32x4*)&segk[kk];
      i32x4 b = *(const i32x4*)&segk[kk + 4];
      #pragma unroll
      for (int j = 0; j < 4; ++j) { sk8[j] = a[j]; sk8[4 + j] = b[j]; }
    } else {
      #pragma unroll
      for (int j = 0; j < 8; ++j) sk8[j] = -1;
    }
    #pragma unroll
    for (int o = 0; o < 8; ++o) {
      const int k = kk + o;
      float v0 = -1e30f, v1 = -1e30f;
      if (k < hiA) {
        const float mb = (sk8[o] == sqA) ? 1.f : 0.f;
        v0 = lg[0][pp][o] + mb; lmax0 = fmaxf(lmax0, v0);
        v1 = lg[1][pp][o] + mb; lmax1 = fmaxf(lmax1, v1);
      }
      lg[0][pp][o] = v0; lg[1][pp][o] = v1;
    }
  }
  #pragma unroll
  for (int m = 1; m < 64; m <<= 1) {
    lmax0 = fmaxf(lmax0, __shfl_xor(lmax0, m));
    lmax1 = fmaxf(lmax1, __shfl_xor(lmax1, m));
  }
  const float M0 = fmaxf(lmax0, 0.f), M1 = fmaxf(lmax1, 0.f);
  float ls0 = 0.f, ls1 = 0.f;
  #pragma unroll
  for (int pp = 0; pp < 2; ++pp)
    #pragma unroll
    for (int o = 0; o < 8; ++o) {
      const float e0 = __expf(lg[0][pp][o] - M0);
      const float e1 = __expf(lg[1][pp][o] - M1);
      lg[0][pp][o] = e0; ls0 += e0;
      lg[1][pp][o] = e1; ls1 += e1;
    }
  #pragma unroll
  for (int m = 1; m < 64; m <<= 1) {
    ls0 += __shfl_xor(ls0, m);
    ls1 += __shfl_xor(ls1, m);
  }
  const float eo0 = __expf(-M0), eo1 = __expf(-M1);
  const float iv0 = 1.f / (ls0 + (float)(Sk - width) * eo0);
  const float iv1 = 1.f / (ls1 + (float)(Sk - width) * eo1);
  const float fv0 = eo0 * iv0, fv1 = eo1 * iv1;

  const int t0 = (q0 >> 7) << 7;
  const int t127 = min(t0 + 127, S - 1);
  const int tLo = (max(bk[segq[max(t0 - 2, 0)]] - 4, 0)) & ~31;
  int tHi = min(bk[segq[min(t127 + 1, S - 1)] + 1] + 4, Sk);
  tHi = min((tHi + 31) & ~31, Sk);

  bfr* row0 = p + ((long long)(c0 + 0) * S + qa) * Sk;
  bfr* row1 = p + ((long long)(c0 + 1) * S + qa) * Sk;
  #pragma unroll
  for (int pp = 0; pp < 2; ++pp) {
    const int kk = loA + pp * 512 + lane * 8;
    if (kk + 7 < hiA) {
      u16x8 s0, s1;
      #pragma unroll
      for (int o = 0; o < 8; ++o) {
        s0[o] = f2bf(lg[0][pp][o] * iv0 - fv0);
        s1[o] = f2bf(lg[1][pp][o] * iv1 - fv1);
      }
      *(u16x8*)(row0 + kk) = s0;
      *(u16x8*)(row1 + kk) = s1;
    } else if (kk < hiA) {
      for (int o = 0; o < 8; ++o)
        if (kk + o < hiA) {
          row0[kk + o] = f2bf(lg[0][pp][o] * iv0 - fv0);
          row1[kk + o] = f2bf(lg[1][pp][o] * iv1 - fv1);
        }
    }
  }
  const u16x4 z4 = {0, 0, 0, 0};
  for (int k = tLo + lane * 4; k < loA; k += 256) {
    *(u16x4*)(row0 + k) = z4;
    *(u16x4*)(row1 + k) = z4;
  }
  for (int k = hiA + lane; k < tHi; k += 64) { row0[k] = 0; row1[k] = 0; }
  if (lane == 0) {
    fvArr[(long long)(h + 0) * S + qa] = fv0;
    fvArr[(long long)(h + 1) * S + qa] = fv1;
  }
}

// ---------------------------------------------------------------------------
// GroupNorm finalize + apply (reads bf16 outb).
// ---------------------------------------------------------------------------
__global__ void gn_finalize(const float* __restrict__ stats, float* __restrict__ mr, float invcnt)
{
  const int g = threadIdx.x;
  if (g < 16) {
    const float s = stats[2 * g], ss = stats[2 * g + 1];
    const float mu = s * invcnt;
    const float var = ss * invcnt - mu * mu;
    mr[2 * g] = mu;
    mr[2 * g + 1] = rsqrtf(var + 1e-5f);
  }
}

__global__ __launch_bounds__(256) void gn_apply(
    const bfr* __restrict__ outb, const float* __restrict__ mr,
    const float* __restrict__ gnw, const float* __restrict__ gnb,
    bfr* __restrict__ y, int S)
{
  const int h = blockIdx.y;
  const long long inner = ((long long)blockIdx.x * 256 + threadIdx.x) * 8;
  if (inner >= (long long)S * D_) return;
  const int s = (int)(inner >> 7), d = (int)(inner & 127);
  const int g = h >> 1;
  const float mu = mr[2 * g], rs = mr[2 * g + 1];
  const float wgt = gnw[h] * rs;
  const float b = gnb[h] - mu * wgt;
  const u16x8 v = *(const u16x8*)(outb + (long long)h * S * D_ + inner);
  u16x8 o;
  #pragma unroll
  for (int j = 0; j < 8; ++j) o[j] = f2bf(bf2f(v[j]) * wgt + b);
  *(u16x8*)(y + (long long)s * HID_ + h * D_ + d) = o;
}

// ---------------------------------------------------------------------------
// Launcher.
// ---------------------------------------------------------------------------
extern "C" void kernel_launch(void* const* d_in, const int* in_sizes, int n_in,
                              void* d_out, int out_size, void* d_ws, size_t ws_size,
                              hipStream_t stream)
{
  const float* x      = (const float*)d_in[0];
  const float* ctx    = (const float*)d_in[1];
  const float* wq     = (const float*)d_in[2];
  const float* wkv    = (const float*)d_in[3];
  const float* wo     = (const float*)d_in[4];
  const float* conv_w = (const float*)d_in[5];
  const float* gnw    = (const float*)d_in[6];
  const float* gnb    = (const float*)d_in[7];
  const void*  qsl    = d_in[8];
  const void*  ksl    = d_in[9];
  const int S    = in_sizes[0] / HID_;   // 1536
  const int Sk   = in_sizes[1] / HID_;   // 1536
  const int nseg = in_sizes[8];          // 4

  auto al = [](size_t v) { return (v + 255) & ~(size_t)255; };
  char* base = (char*)d_ws;
  size_t off = 0;
  auto take = [&](size_t bytes) -> char* { char* r = base + off; off += al(bytes); return r; };

  int*   segq  = (int*)take((size_t)S * 4);
  int*   segk  = (int*)take((size_t)Sk * 4);
  int*   bq    = (int*)take(64);
  int*   bk    = (int*)take(64);
  float* stats = (float*)take(128);
  float* mr    = (float*)take(128);
  float* fvArr = (float*)take((size_t)H_ * S * 4);
  float* csV   = (float*)take((size_t)H_ * D_ * 4);
  bfr*   qb    = (bfr*)take((size_t)H_ * S * D_ * 2);
  bfr*   kbuf  = (bfr*)take((size_t)H_ * Sk * D_ * 2);
  bfr*   vrow  = (bfr*)take((size_t)H_ * Sk * D_ * 2);
  bfr*   vt    = (bfr*)take((size_t)H_ * Sk * D_ * 2);
  bfr*   outb  = (bfr*)take((size_t)H_ * S * D_ * 2);   // bf16
  const size_t poolBase = off;
  char*  pool  = base + poolBase;

  const int Smax = (S > Sk) ? S : Sk;
  const size_t A1 = al((size_t)Smax * HID_ * 2);
  const size_t WT = al((size_t)HID_ * HID_ * 2);
  const size_t PART = al((size_t)2 * S * HID_ * 4);

  const size_t CAmin = al((size_t)4 * S * Sk * 2);
  const size_t fusedNeed = (A1 + 2 * WT > 2 * CAmin) ? (A1 + 2 * WT) : (2 * CAmin);
  const bool fused = (poolBase + fusedNeed <= ws_size);
  const bool splitOK = (poolBase + A1 + 2 * WT + PART <= ws_size);
  const size_t wNeed = A1 + (fused ? 2 : 1) * WT + (splitOK ? PART : 0);

  int nc = 4;
  {
    const int cands[3] = {32, 16, 8};
    for (int ci = 0; ci < 3; ++ci) {
      const size_t CA = al((size_t)cands[ci] * S * Sk * 2);
      const size_t need = (wNeed > 2 * CA) ? wNeed : (2 * CA);
      if (poolBase + need <= ws_size) { nc = cands[ci]; break; }
    }
  }
  const size_t CA = al((size_t)nc * S * Sk * 2);
  bfr*   xcb    = (bfr*)pool;
  bfr*   wT     = (bfr*)(pool + A1);
  float* partB  = (float*)(pool + A1 + 2 * WT);
  bfr*   attn_c = (bfr*)pool;
  bfr*   pbuf_c = (bfr*)(pool + CA);

  seg_setup<<<1, 256, 0, stream>>>(qsl, ksl, segq, segk, bq, bk, stats, S, Sk, nseg);

  GemmAux aux{};
  aux.segq = segq; aux.segk = segk; aux.bk = bk;
  aux.qb = qb; aux.kb = kbuf; aux.vrow = vrow;
  aux.outb = nullptr; aux.outb16 = outb; aux.stats = stats;
  aux.fvArr = fvArr; aux.colsum = csV;
  aux.scale = 0.08838834764831845f;  // 1/sqrt(128)
  aux.S = S; aux.Sk = Sk; aux.nOff = 0;

  const long long MN = (long long)S * HID_;
  const int nRed = (int)((MN / 8 + 255) / 256);

  // ---- Q projection ----
  const long long nx = (long long)S * HID_;
  cvt_bf16<<<(int)((nx / 8 + 255) / 256), 256, 0, stream>>>(x, xcb, nx);
  transpose_cvt<<<dim3(HID_ / 64, HID_ / 64), 256, 0, stream>>>(wq, wT, HID_, HID_);
  if (splitOK) {
    GemmAux auxQ = aux; auxQ.outb = partB;
    gemm_bt<MODE_Q, 2, 64><<<dim3(HID_ / 128, S / 128, 2), 256, 0, stream>>>(
        xcb, wT, nullptr, HID_, HID_, HID_, HID_, 0, 0, 0, auxQ);
    reduce_split_q<<<nRed, 256, 0, stream>>>(partB, qb, aux.scale, S);
  } else {
    gemm_bt<MODE_Q, 1, 64><<<dim3(HID_ / 128, S / 128, 1), 256, 0, stream>>>(
        xcb, wT, nullptr, HID_, HID_, HID_, HID_, 0, 0, 0, aux);
  }

  // ---- KV projection ----
  const long long nctx = (long long)Sk * HID_;
  cvt_bf16<<<(int)((nctx / 8 + 255) / 256), 256, 0, stream>>>(ctx, xcb, nctx);
  if (fused) {
    transpose_cvt<<<dim3(2 * HID_ / 64, HID_ / 64), 256, 0, stream>>>(wkv, wT, HID_, 2 * HID_);
    gemm_bt<MODE_KV, 1, 64><<<dim3(2 * HID_ / 128, Sk / 128, 1), 256, 0, stream>>>(
        xcb, wT, nullptr, 2 * HID_, HID_, HID_, HID_, 0, 0, 0, aux);
  } else {
    transpose_cvt<<<dim3(HID_ / 64, HID_ / 64), 256, 0, stream>>>(wkv, wT, HID_, 2 * HID_);
    gemm_bt<MODE_KV, 1, 64><<<dim3(HID_ / 128, Sk / 128, 1), 256, 0, stream>>>(
        xcb, wT, nullptr, HID_, HID_, HID_, HID_, 0, 0, 0, aux);
    transpose_cvt<<<dim3(HID_ / 64, HID_ / 64), 256, 0, stream>>>(wkv + HID_, wT, HID_, 2 * HID_);
    GemmAux auxV = aux; auxV.nOff = H_ * D_;
    gemm_bt<MODE_KV, 1, 64><<<dim3(HID_ / 128, Sk / 128, 1), 256, 0, stream>>>(
        xcb, wT, nullptr, HID_, HID_, HID_, HID_, 0, 0, 0, auxV);
  }

  // ---- V transpose + column sums ----
  transpose_b16<<<dim3(D_ / 64, Sk / 64, H_), 256, 0, stream>>>(vrow, vt, Sk, D_);
  colsum_v<<<H_ * D_ / 4, 256, 0, stream>>>(vt, csV, Sk);

  // ---- attention, chunked over heads ----
  for (int h0 = 0; h0 < H_; h0 += nc) {
    gemm_qk<<<dim3(Sk / 128, S / 128, nc), 256, 0, stream>>>(
        qb + (size_t)h0 * S * D_, kbuf + (size_t)h0 * Sk * D_, attn_c,
        (long long)S * D_, (long long)Sk * D_, (long long)S * Sk, aux);
    conv_softmax9<<<dim3(S / 4, nc / 2), 256, 0, stream>>>(
        attn_c, conv_w, pbuf_c, fvArr, segq, segk, bk, S, Sk, h0);
    GemmAux auxP = aux;
    auxP.outb16 = outb + (size_t)h0 * S * D_;
    auxP.stats = stats + h0;
    auxP.fvArr = fvArr + (size_t)h0 * S;
    auxP.colsum = csV + (size_t)h0 * D_;
    gemm_bt<MODE_PV, 1, 32><<<dim3(1, S / 128, nc), 256, 0, stream>>>(
        pbuf_c, vt + (size_t)h0 * D_ * Sk, nullptr,
        D_, Sk, Sk, Sk,
        (long long)S * Sk, (long long)D_ * Sk, 0, auxP);
  }

  // ---- GroupNorm + output projection ----
  gn_finalize<<<1, 32, 0, stream>>>(stats, mr, 1.0f / (2.0f * S * D_));
  gn_apply<<<dim3((S * D_) / 2048, H_), 256, 0, stream>>>(outb, mr, gnw, gnb, xcb, S);
  transpose_cvt<<<dim3(HID_ / 64, HID_ / 64), 256, 0, stream>>>(wo, wT, HID_, HID_);
  if (splitOK) {
    GemmAux auxO = aux; auxO.outb = partB;
    gemm_bt<MODE_PLAIN, 2, 64><<<dim3(HID_ / 128, S / 128, 2), 256, 0, stream>>>(
        xcb, wT, nullptr, HID_, HID_, HID_, HID_, 0, 0, 0, auxO);
    reduce_split_f32<<<nRed, 256, 0, stream>>>(partB, (float*)d_out, MN);
  } else {
    gemm_bt<MODE_PLAIN, 1, 64><<<dim3(HID_ / 128, S / 128, 1), 256, 0, stream>>>(
        xcb, wT, d_out, HID_, HID_, HID_, HID_, 0, 0, 0, aux);
  }
}

// Round 19
// 504.732 us; speedup vs baseline: 1.0155x; 1.0039x over previous
//
#include <hip/hip_runtime.h>
#include <stdint.h>

// ---------------------------------------------------------------------------
// MT_Attention fused pipeline, round 19 = round 16/18 base (506us) +
// conv_softmax10: head-pair accumulators packed as f32x2 so LLVM can emit
// v_pk_fma_f32 (2 FMAs/instr) — conv's 2304 scalar FMAs/lane were the
// dominant VALU issue cost. Neutral if pk ops aren't selected.
// ---------------------------------------------------------------------------

#define H_   32
#define D_   128
#define HID_ 4096
#define WMAX2 944
#define LPAD 8

typedef unsigned short bfr;  // raw bf16 bits
typedef __attribute__((ext_vector_type(2))) float f32x2;
typedef __attribute__((ext_vector_type(4))) float f32x4;
typedef __attribute__((ext_vector_type(4))) int   i32x4;
typedef __attribute__((ext_vector_type(8))) unsigned short u16x8;
typedef __attribute__((ext_vector_type(4))) unsigned short u16x4;

__device__ __forceinline__ bfr f2bf(float f) {
  uint32_t u = __float_as_uint(f);
  u += 0x7fffu + ((u >> 16) & 1u);   // RNE
  return (bfr)(u >> 16);
}
__device__ __forceinline__ float bf2f(bfr u) {
  return __uint_as_float(((uint32_t)u) << 16);
}
__device__ __forceinline__ void mfma_bf16(f32x4& d, i32x4 a, i32x4 b) {
  asm volatile("v_mfma_f32_16x16x32_bf16 %0, %1, %2, %0" : "+v"(d) : "v"(a), "v"(b));
}
__device__ __forceinline__ void gload_lds16(const void* g, void* l) {
  __builtin_amdgcn_global_load_lds((__attribute__((address_space(1))) void*)g,
                                   (__attribute__((address_space(3))) void*)l,
                                   16, 0, 0);
}

// ---------------------------------------------------------------------------
// Segment setup.
// ---------------------------------------------------------------------------
__global__ __launch_bounds__(256) void seg_setup(
    const void* __restrict__ qsl, const void* __restrict__ ksl,
    int* __restrict__ segq, int* __restrict__ segk,
    int* __restrict__ bq, int* __restrict__ bk,
    float* __restrict__ stats, int S, int Sk, int nseg)
{
  __shared__ int sbq[16], sbk[16];
  const int tid = threadIdx.x;
  if (tid == 0) {
    {
      const int* q32 = (const int*)qsl;
      long long s32 = 0; bool ok32 = true;
      for (int i = 0; i < nseg; ++i) { int v = q32[i]; if (v < 1 || v > S) ok32 = false; s32 += v; }
      const bool use32 = ok32 && (s32 == S);
      const long long* q64 = (const long long*)qsl;
      sbq[0] = 0;
      for (int i = 0; i < nseg; ++i) sbq[i + 1] = sbq[i] + (use32 ? q32[i] : (int)q64[i]);
    }
    {
      const int* k32 = (const int*)ksl;
      long long s32 = 0; bool ok32 = true;
      for (int i = 0; i < nseg; ++i) { int v = k32[i]; if (v < 1 || v > Sk) ok32 = false; s32 += v; }
      const bool use32 = ok32 && (s32 == Sk);
      const long long* k64 = (const long long*)ksl;
      sbk[0] = 0;
      for (int i = 0; i < nseg; ++i) sbk[i + 1] = sbk[i] + (use32 ? k32[i] : (int)k64[i]);
    }
    for (int i = 0; i <= nseg; ++i) { bq[i] = sbq[i]; bk[i] = sbk[i]; }
  }
  if (tid < 32) stats[tid] = 0.f;
  __syncthreads();
  for (int i = tid; i < S; i += 256) {
    int s = 0;
    while (s < nseg - 1 && i >= sbq[s + 1]) ++s;
    segq[i] = s;
  }
  for (int i = tid; i < Sk; i += 256) {
    int s = 0;
    while (s < nseg - 1 && i >= sbk[s + 1]) ++s;
    segk[i] = s;
  }
}

// ---------------------------------------------------------------------------
// Elementwise f32 -> bf16.
// ---------------------------------------------------------------------------
__global__ __launch_bounds__(256) void cvt_bf16(
    const float* __restrict__ in, bfr* __restrict__ out, long long n)
{
  long long i = ((long long)blockIdx.x * 256 + threadIdx.x) * 8;
  if (i >= n) return;
  f32x4 a = *(const f32x4*)(in + i);
  f32x4 b = *(const f32x4*)(in + i + 4);
  u16x8 o;
  #pragma unroll
  for (int j = 0; j < 4; ++j) { o[j] = f2bf(a[j]); o[4 + j] = f2bf(b[j]); }
  *(u16x8*)(out + i) = o;
}

// ---------------------------------------------------------------------------
// Tiled transpose + f32->bf16, source row stride ld.
// ---------------------------------------------------------------------------
__global__ __launch_bounds__(256) void transpose_cvt(
    const float* __restrict__ in, bfr* __restrict__ out, int R, int ld)
{
  __shared__ float tile[64][65];
  const int t = threadIdx.x;
  const int rb = blockIdx.y * 64, cb = blockIdx.x * 64;
  const int row = t >> 2, c4 = (t & 3) * 16;
  const float* gp = in + (long long)(rb + row) * ld + cb + c4;
  #pragma unroll
  for (int j = 0; j < 4; ++j) {
    f32x4 v = *(const f32x4*)(gp + j * 4);
    #pragma unroll
    for (int q = 0; q < 4; ++q) tile[row][c4 + j * 4 + q] = v[q];
  }
  __syncthreads();
  const int cc = row, r4 = c4;
  u16x8 a, b;
  #pragma unroll
  for (int j = 0; j < 8; ++j) a[j] = f2bf(tile[r4 + j][cc]);
  #pragma unroll
  for (int j = 0; j < 8; ++j) b[j] = f2bf(tile[r4 + 8 + j][cc]);
  bfr* op = out + (long long)(cb + cc) * R + rb + r4;
  *(u16x8*)op = a;
  *(u16x8*)(op + 8) = b;
}

// ---------------------------------------------------------------------------
// Per-head bf16 transpose: in [R][C] -> out [C][R], z = head.
// ---------------------------------------------------------------------------
__global__ __launch_bounds__(256) void transpose_b16(
    const bfr* __restrict__ in, bfr* __restrict__ out, int R, int C)
{
  __shared__ bfr t[64][72];
  const int z = blockIdx.z;
  const bfr* ip = in + (long long)z * R * C;
  bfr* op = out + (long long)z * R * C;
  const int rb = blockIdx.y * 64, cb = blockIdx.x * 64;
  const int tr = threadIdx.x >> 3;
  const int tc = (threadIdx.x & 7) * 8;
  #pragma unroll
  for (int half = 0; half < 2; ++half) {
    const int r = tr + half * 32;
    u16x8 v = *(const u16x8*)(ip + (long long)(rb + r) * C + cb + tc);
    *(u16x8*)&t[r][tc] = v;
  }
  __syncthreads();
  #pragma unroll
  for (int half = 0; half < 2; ++half) {
    const int cc = tr + half * 32;
    u16x8 vv;
    #pragma unroll
    for (int j = 0; j < 8; ++j) vv[j] = t[tc + j][cc];
    *(u16x8*)(op + (long long)(cb + cc) * R + rb + tc) = vv;
  }
}

// ---------------------------------------------------------------------------
// Column sums of V^T rows.
// ---------------------------------------------------------------------------
__global__ __launch_bounds__(256) void colsum_v(
    const bfr* __restrict__ vt, float* __restrict__ cs, int Sk)
{
  const int lane = threadIdx.x & 63, wave = threadIdx.x >> 6;
  const int row = blockIdx.x * 4 + wave;
  const bfr* src = vt + (long long)row * Sk;
  float s = 0.f;
  for (int i = lane * 8; i + 8 <= Sk; i += 512) {
    u16x8 v = *(const u16x8*)(src + i);
    #pragma unroll
    for (int j = 0; j < 8; ++j) s += bf2f(v[j]);
  }
  #pragma unroll
  for (int m = 1; m < 64; m <<= 1) s += __shfl_xor(s, m);
  if (lane == 0) cs[row] = s;
}

// ---------------------------------------------------------------------------
struct GemmAux {
  const int* segq; const int* segk; const int* bk;
  bfr* qb; bfr* kb; bfr* vrow;
  float* outb;          // split-K f32 partials
  bfr* outb16;          // PV bf16 output
  float* stats;
  const float* fvArr; const float* colsum;
  float scale;
  int S, Sk, nOff;
};

enum { MODE_PLAIN = 0, MODE_Q = 1, MODE_KV = 2, MODE_QK = 3, MODE_PV = 4 };

// ---------------------------------------------------------------------------
// 4-wave BT GEMM, 128x128 tile, single-buffer lockstep loop, zero-conflict
// XOR swizzle. BKL = K-step (32 or 64). KS>1 = split-K (z = slice).
// ---------------------------------------------------------------------------
template <int MODE, int KS = 1, int BKL = 32>
__global__ __launch_bounds__(256) void gemm_bt(
    const bfr* __restrict__ A, const bfr* __restrict__ Bt, void* __restrict__ Cout,
    int N, int K, int lda, int ldb,
    long long aZ, long long bZ, long long cZ, GemmAux aux)
{
  __shared__ bfr As[128 * BKL];
  __shared__ bfr Bs[128 * BKL];
  __shared__ float redS[8], redSS[8];
  const int tid = threadIdx.x;
  const int lane = tid & 63;
  const int wave = tid >> 6;
  const int z = blockIdx.z;

  int bx = blockIdx.x, by = blockIdx.y;
  {
    const int gx = gridDim.x, gy = gridDim.y;
    if (((gx & 3) == 0) && ((gy & 1) == 0)) {
      const int lid = by * gx + bx;
      const int xcd = lid & 7, inner = lid >> 3;
      const int cm = gy >> 1, cn = gx >> 2;
      by = (xcd >> 2) * cm + inner / cn;
      bx = (xcd & 3) * cn + inner % cn;
    }
  }
  const int m0 = by * 128;
  const int n0 = bx * 128;
  const bfr* Ap = A + (long long)z * aZ;
  const bfr* Bp = Bt + (long long)z * bZ;

  int kLo = 0, kHiV = K;
  if constexpr (KS > 1) { const int ksp = K / KS; kLo = z * ksp; kHiV = kLo + ksp; }
  if constexpr (MODE == MODE_PV) {
    const int t127 = min(m0 + 127, aux.S - 1);
    kLo = (max(aux.bk[aux.segq[max(m0 - 2, 0)]] - 4, 0)) & ~31;
    int th = min(aux.bk[aux.segq[min(t127 + 1, aux.S - 1)] + 1] + 4, aux.Sk);
    kHiV = min((th + 31) & ~31, aux.Sk);
  }

  const int wr = (wave >> 1) * 64;
  const int wc = (wave & 1) * 64;
  f32x4 acc[4][4];
  #pragma unroll
  for (int i = 0; i < 4; ++i)
    #pragma unroll
    for (int j = 0; j < 4; ++j) acc[i][j] = (f32x4){0.f, 0.f, 0.f, 0.f};

  // BK=32 swizzle (64B rows, 4 slots): key (R>>1)&3. Verified r9/r10: 0 conflicts.
  const int srow32 = lane >> 2;
  const int scol32 = (((lane & 3) ^ ((lane >> 3) & 3)) << 3);
  const int rcol32 = (((lane >> 4) ^ ((lane >> 1) & 3)) << 3);
  // BK=64 swizzle (128B rows, 8 slots of 16B): key row&7. Verified r11: 0 conflicts.
  const int srow64 = lane >> 3;
  const int scol64 = (((lane & 7) ^ ((lane >> 3) & 7)) << 3);

  const int kSteps = (kHiV - kLo) >> (BKL == 32 ? 5 : 6);
  for (int ks = 0; ks < kSteps; ++ks) {
    const int k0 = kLo + ks * BKL;
    if constexpr (BKL == 32) {
      #pragma unroll
      for (int c = 0; c < 4; ++c) {
        const int chunk = (wave << 2) + c;
        const int ci = chunk & 7;
        const int row = ci * 16 + srow32;
        if (chunk < 8) gload_lds16(Ap + (long long)(m0 + row) * lda + k0 + scol32, As + ci * 512);
        else           gload_lds16(Bp + (long long)(n0 + row) * ldb + k0 + scol32, Bs + ci * 512);
      }
    } else {
      #pragma unroll
      for (int c = 0; c < 8; ++c) {
        const int chunk = wave * 8 + c;           // 0..31: 16 A + 16 B chunks (1KB each)
        const int ci = chunk & 15;
        const int row = ci * 8 + srow64;
        if (chunk < 16) gload_lds16(Ap + (long long)(m0 + row) * lda + k0 + scol64, As + ci * 512);
        else            gload_lds16(Bp + (long long)(n0 + row) * ldb + k0 + scol64, Bs + ci * 512);
      }
    }
    __syncthreads();   // lockstep: keeps co-resident blocks' K-phases aligned (L2)
    if constexpr (BKL == 32) {
      i32x4 af[4], bfv[4];
      #pragma unroll
      for (int i = 0; i < 4; ++i)
        af[i] = *(const i32x4*)&As[(wr + i * 16 + (lane & 15)) * 32 + rcol32];
      #pragma unroll
      for (int i = 0; i < 4; ++i)
        bfv[i] = *(const i32x4*)&Bs[(wc + i * 16 + (lane & 15)) * 32 + rcol32];
      #pragma unroll
      for (int i = 0; i < 4; ++i)
        #pragma unroll
        for (int j = 0; j < 4; ++j)
          mfma_bf16(acc[i][j], af[i], bfv[j]);
    } else {
      #pragma unroll
      for (int ks2 = 0; ks2 < 2; ++ks2) {
        const int rcol = (((ks2 * 4 + (lane >> 4)) ^ (lane & 7)) << 3);
        i32x4 af[4], bfv[4];
        #pragma unroll
        for (int i = 0; i < 4; ++i)
          af[i] = *(const i32x4*)&As[(wr + i * 16 + (lane & 15)) * 64 + rcol];
        #pragma unroll
        for (int i = 0; i < 4; ++i)
          bfv[i] = *(const i32x4*)&Bs[(wc + i * 16 + (lane & 15)) * 64 + rcol];
        #pragma unroll
        for (int i = 0; i < 4; ++i)
          #pragma unroll
          for (int j = 0; j < 4; ++j)
            mfma_bf16(acc[i][j], af[i], bfv[j]);
      }
    }
    __syncthreads();
  }

  float fvm[16], csn[4];
  if constexpr (MODE == MODE_PV) {
    #pragma unroll
    for (int i = 0; i < 4; ++i)
      #pragma unroll
      for (int r = 0; r < 4; ++r)
        fvm[i * 4 + r] = aux.fvArr[(long long)z * aux.S + m0 + wr + i * 16 + (lane >> 4) * 4 + r];
    #pragma unroll
    for (int j = 0; j < 4; ++j)
      csn[j] = aux.colsum[(long long)z * D_ + n0 + wc + j * 16 + (lane & 15)];
  }

  float sv = 0.f, sq2 = 0.f;
  #pragma unroll
  for (int i = 0; i < 4; ++i) {
    #pragma unroll
    for (int j = 0; j < 4; ++j) {
      #pragma unroll
      for (int r = 0; r < 4; ++r) {
        const int m = m0 + wr + i * 16 + (lane >> 4) * 4 + r;
        const int n = n0 + wc + j * 16 + (lane & 15);
        const float v = acc[i][j][r];
        if constexpr (KS > 1) {
          aux.outb[((long long)z * aux.S + m) * N + n] = v;   // f32 partial
        } else if constexpr (MODE == MODE_PLAIN) {
          ((float*)Cout)[(long long)m * N + n] = v;
        } else if constexpr (MODE == MODE_Q) {
          const int hh = n >> 7, d = n & 127;
          aux.qb[((long long)hh * aux.S + m) * D_ + d] = f2bf(v * aux.scale);
        } else if constexpr (MODE == MODE_KV) {
          const int ng = n + aux.nOff;
          if (ng < H_ * D_) {
            const int hh = ng >> 7, d = ng & 127;
            aux.kb[((long long)hh * aux.Sk + m) * D_ + d] = f2bf(v);
          } else {
            const int nv = ng - H_ * D_;
            const int hh = nv >> 7, d = nv & 127;
            aux.vrow[((long long)hh * aux.Sk + m) * D_ + d] = f2bf(v);
          }
        } else if constexpr (MODE == MODE_PV) {
          const float vv = v + fvm[i * 4 + r] * csn[j];
          aux.outb16[((long long)z * aux.S + m) * D_ + n] = f2bf(vv);
          sv += vv; sq2 += vv * vv;
        }
      }
    }
  }

  if constexpr (MODE == MODE_PV && KS == 1) {
    #pragma unroll
    for (int msk = 1; msk < 64; msk <<= 1) {
      sv  += __shfl_xor(sv, msk);
      sq2 += __shfl_xor(sq2, msk);
    }
    if (lane == 0) { redS[wave] = sv; redSS[wave] = sq2; }
    __syncthreads();
    if (tid == 0) {
      const float a = redS[0] + redS[1] + redS[2] + redS[3];
      const float b = redSS[0] + redSS[1] + redSS[2] + redSS[3];
      atomicAdd(&aux.stats[(z >> 1) * 2 + 0], a);
      atomicAdd(&aux.stats[(z >> 1) * 2 + 1], b);
    }
  }
}

// ---------------------------------------------------------------------------
// gemm_qk: K = D = 128 staged entirely in LDS, ONE barrier, 64 MFMA/wave.
// ---------------------------------------------------------------------------
__global__ __launch_bounds__(256) void gemm_qk(
    const bfr* __restrict__ A, const bfr* __restrict__ Bt, bfr* __restrict__ Cout,
    long long aZ, long long bZ, long long cZ, GemmAux aux)
{
  __shared__ bfr As[128 * 128];
  __shared__ bfr Bs[128 * 128];
  const int tid = threadIdx.x;
  const int lane = tid & 63;
  const int wave = tid >> 6;
  const int z = blockIdx.z;
  const int m0 = blockIdx.y * 128;
  const int n0 = blockIdx.x * 128;

  const int t127 = min(m0 + 127, aux.S - 1);
  const int loT = max(aux.bk[aux.segq[max(m0 - 2, 0)]] - 4, 0);
  const int hiT = min(aux.bk[aux.segq[min(t127 + 1, aux.S - 1)] + 1] + 4, aux.Sk);
  if (n0 > hiT + 16 || n0 + 127 < loT - 16) return;
  const int sm0 = aux.segq[m0], sm1 = aux.segq[t127];
  const int sn0 = aux.segk[n0], sn1 = aux.segk[min(n0 + 127, aux.Sk - 1)];
  if (sm1 < sn0 || sn1 < sm0) {
    bfr* C = Cout + (long long)z * cZ + (long long)m0 * aux.Sk + n0;
    const i32x4 zz = {0, 0, 0, 0};
    #pragma unroll
    for (int c = 0; c < 8; ++c) {
      int id = c * 256 + tid;
      int r = id >> 4, col = (id & 15) * 8;
      *(i32x4*)(C + (long long)r * aux.Sk + col) = zz;
    }
    return;
  }

  const bfr* Ap = A + (long long)z * aZ;
  const bfr* Bp = Bt + (long long)z * bZ;

  const int srow = lane >> 4;
  #pragma unroll
  for (int c = 0; c < 16; ++c) {
    const int chunk = wave * 16 + c;
    const int cl = chunk & 31;
    const int f = (2 * cl + (lane >> 5)) & 7;
    const int sc = ((lane & 15) ^ f) * 8;
    const int r = cl * 4 + srow;
    if (chunk < 32) gload_lds16(Ap + (long long)(m0 + r) * D_ + sc, As + cl * 512);
    else            gload_lds16(Bp + (long long)(n0 + r) * D_ + sc, Bs + cl * 512);
  }
  __syncthreads();

  const int wr = (wave >> 1) * 64;
  const int wc = (wave & 1) * 64;
  f32x4 acc[4][4];
  #pragma unroll
  for (int i = 0; i < 4; ++i)
    #pragma unroll
    for (int j = 0; j < 4; ++j) acc[i][j] = (f32x4){0.f, 0.f, 0.f, 0.f};

  const int rf = (lane >> 1) & 7;
  #pragma unroll
  for (int ks = 0; ks < 4; ++ks) {
    const int slot = (4 * ks + (lane >> 4)) ^ rf;
    const int colb = slot * 8;
    i32x4 af[4], bfv[4];
    #pragma unroll
    for (int i = 0; i < 4; ++i)
      af[i] = *(const i32x4*)&As[(wr + i * 16 + (lane & 15)) * 128 + colb];
    #pragma unroll
    for (int j = 0; j < 4; ++j)
      bfv[j] = *(const i32x4*)&Bs[(wc + j * 16 + (lane & 15)) * 128 + colb];
    #pragma unroll
    for (int i = 0; i < 4; ++i)
      #pragma unroll
      for (int j = 0; j < 4; ++j)
        mfma_bf16(acc[i][j], af[i], bfv[j]);
  }

  const bool qkUni = (sm0 == sm1) && (sn0 == sn1);
  int sgm[16], sgn[4];
  if (!qkUni) {
    #pragma unroll
    for (int i = 0; i < 4; ++i)
      #pragma unroll
      for (int r = 0; r < 4; ++r)
        sgm[i * 4 + r] = aux.segq[m0 + wr + i * 16 + (lane >> 4) * 4 + r];
    #pragma unroll
    for (int j = 0; j < 4; ++j) sgn[j] = aux.segk[n0 + wc + j * 16 + (lane & 15)];
  }
  #pragma unroll
  for (int i = 0; i < 4; ++i) {
    #pragma unroll
    for (int j = 0; j < 4; ++j) {
      #pragma unroll
      for (int r = 0; r < 4; ++r) {
        const int m = m0 + wr + i * 16 + (lane >> 4) * 4 + r;
        const int n = n0 + wc + j * 16 + (lane & 15);
        const float v = acc[i][j][r];
        const float vv = (qkUni || sgm[i * 4 + r] == sgn[j]) ? v : 0.f;
        Cout[(long long)z * cZ + (long long)m * aux.Sk + n] = f2bf(vv);
      }
    }
  }
}

// ---------------------------------------------------------------------------
// Split-K reduces.
// ---------------------------------------------------------------------------
__global__ __launch_bounds__(256) void reduce_split_q(
    const float* __restrict__ part, bfr* __restrict__ qb, float scale, int S)
{
  const long long MN = (long long)S * HID_;
  const long long i = ((long long)blockIdx.x * 256 + threadIdx.x) * 8;
  if (i >= MN) return;
  const f32x4 a0 = *(const f32x4*)(part + i);
  const f32x4 a1 = *(const f32x4*)(part + i + 4);
  const f32x4 b0 = *(const f32x4*)(part + MN + i);
  const f32x4 b1 = *(const f32x4*)(part + MN + i + 4);
  const int m = (int)(i >> 12);
  const int n = (int)(i & 4095);
  const int hh = n >> 7, d = n & 127;
  u16x8 o;
  #pragma unroll
  for (int j = 0; j < 4; ++j) {
    o[j]     = f2bf((a0[j] + b0[j]) * scale);
    o[4 + j] = f2bf((a1[j] + b1[j]) * scale);
  }
  *(u16x8*)(qb + ((long long)hh * S + m) * D_ + d) = o;
}

__global__ __launch_bounds__(256) void reduce_split_f32(
    const float* __restrict__ part, float* __restrict__ out, long long MN)
{
  const long long i = ((long long)blockIdx.x * 256 + threadIdx.x) * 8;
  if (i >= MN) return;
  const f32x4 a0 = *(const f32x4*)(part + i);
  const f32x4 a1 = *(const f32x4*)(part + i + 4);
  const f32x4 b0 = *(const f32x4*)(part + MN + i);
  const f32x4 b1 = *(const f32x4*)(part + MN + i + 4);
  f32x4 o0, o1;
  #pragma unroll
  for (int j = 0; j < 4; ++j) { o0[j] = a0[j] + b0[j]; o1[j] = a1[j] + b1[j]; }
  *(f32x4*)(out + i) = o0;
  *(f32x4*)(out + i + 4) = o1;
}

// ---------------------------------------------------------------------------
// Banded conv(4x9) + softmax, head-pair, 256 thr, 4 q-rows/block, 8 out/lane.
// v10: f32x2 packed accumulators (head0, head1) -> v_pk_fma_f32 eligible.
// ---------------------------------------------------------------------------
__global__ __launch_bounds__(256) void conv_softmax10(
    const bfr* __restrict__ attn, const float* __restrict__ conv_w,
    bfr* __restrict__ p, float* __restrict__ fvArr,
    const int* __restrict__ segq, const int* __restrict__ segk,
    const int* __restrict__ bk, int S, int Sk, int h0)
{
  __shared__ float wsh[144];
  __shared__ bfr sIn[7][WMAX2];
  const int tid = threadIdx.x, lane = tid & 63, w = tid >> 6;
  const int q0 = blockIdx.x * 4;
  const int c0 = blockIdx.y * 2;
  const int h  = h0 + c0;
  if (tid < 144) wsh[tid] = conv_w[h * 72 + tid];

  const int lo0 = (max(bk[segq[max(q0 - 2, 0)]] - 4, 0)) & ~7;
  const int hiL = min(bk[segq[min(q0 + 4, S - 1)] + 1] + 4, Sk);
  const int g0 = max(lo0 - 8, 0) & ~7;
  const int g1 = min(hiL + 4, Sk);
  const int W8 = (g1 - g0 + 7) >> 3;

  const int qa = q0 + w;
  const int loA = (max(bk[segq[max(qa - 2, 0)]] - 4, 0)) & ~7;
  const int hiA = min(bk[segq[min(qa + 1, S - 1)] + 1] + 4, Sk);
  const int sqA = segq[qa];
  const int width = hiA - loA;

  f32x2 lg2[2][8];                      // [pp][o] = {head0, head1}
  #pragma unroll
  for (int pp = 0; pp < 2; ++pp)
    #pragma unroll
    for (int o = 0; o < 8; ++o) lg2[pp][o] = (f32x2){0.f, 0.f};

  if (tid < 7) {
    const u16x8 zz8 = {0,0,0,0,0,0,0,0};
    *(u16x8*)&sIn[tid][0] = zz8;
    *(u16x8*)&sIn[tid][LPAD + W8 * 8] = zz8;
  }

  for (int pass = 0; pass < 2; ++pass) {
    if (pass) __syncthreads();
    const bfr* src0 = attn + (long long)(c0 + pass) * S * Sk;
    for (int it = tid; it < 7 * 116; it += 256) {
      const int ri = it / 116;
      const int j  = it - ri * 116;
      if (j < W8) {
        const int r = q0 - 2 + ri;
        u16x8 v = {0,0,0,0,0,0,0,0};
        if (r >= 0 && r < S) v = *(const u16x8*)(src0 + (long long)r * Sk + g0 + j * 8);
        *(u16x8*)&sIn[ri][LPAD + j * 8] = v;
      }
    }
    __syncthreads();

    #pragma unroll
    for (int pp = 0; pp < 2; ++pp) {
      const int kk = loA + pp * 512 + lane * 8;
      if (kk < hiA) {
        const int ib2 = LPAD + kk - 8 - g0;   // 16B-aligned
        #pragma unroll
        for (int rr = 0; rr < 4; ++rr) {
          const bfr* sp = &sIn[w + rr][ib2];
          u16x8 u0 = *(const u16x8*)(sp);
          u16x8 u1 = *(const u16x8*)(sp + 8);
          u16x8 u2 = *(const u16x8*)(sp + 16);
          float xx[16];                         // xx[i] = pos kk-4+i
          #pragma unroll
          for (int j2 = 0; j2 < 4; ++j2) {
            xx[j2]      = bf2f(u0[4 + j2]);
            xx[4 + j2]  = bf2f(u1[j2]);
            xx[8 + j2]  = bf2f(u1[4 + j2]);
            xx[12 + j2] = bf2f(u2[j2]);
          }
          const float* wv0 = &wsh[(pass * 4 + rr) * 9];
          const float* wv1 = wv0 + 72;
          #pragma unroll
          for (int dk = 0; dk < 9; ++dk) {
            const f32x2 wp = {wv0[dk], wv1[dk]};   // packed head-pair weights
            #pragma unroll
            for (int o = 0; o < 8; ++o)
              lg2[pp][o] += wp * xx[o + dk];       // -> v_pk_fma_f32
          }
        }
      }
    }
  }

  float lmax0 = -1e30f, lmax1 = -1e30f;
  #pragma unroll
  for (int pp = 0; pp < 2; ++pp) {
    const int kk = loA + pp * 512 + lane * 8;
    int sk8[8];
    if (kk < Sk) {
      i32x4 a = *(const i32x4*)&segk[kk];
      i32x4 b = *(const i32x4*)&segk[kk + 4];
      #pragma unroll
      for (int j = 0; j < 4; ++j) { sk8[j] = a[j]; sk8[4 + j] = b[j]; }
    } else {
      #pragma unroll
      for (int j = 0; j < 8; ++j) sk8[j] = -1;
    }
    #pragma unroll
    for (int o = 0; o < 8; ++o) {
      const int k = kk + o;
      if (k < hiA) {
        const float mb = (sk8[o] == sqA) ? 1.f : 0.f;
        const f32x2 t = lg2[pp][o] + mb;
        lmax0 = fmaxf(lmax0, t[0]);
        lmax1 = fmaxf(lmax1, t[1]);
        lg2[pp][o] = t;
      } else {
        lg2[pp][o] = (f32x2){-1e30f, -1e30f};
      }
    }
  }
  #pragma unroll
  for (int m = 1; m < 64; m <<= 1) {
    lmax0 = fmaxf(lmax0, __shfl_xor(lmax0, m));
    lmax1 = fmaxf(lmax1, __shfl_xor(lmax1, m));
  }
  const float M0 = fmaxf(lmax0, 0.f), M1 = fmaxf(lmax1, 0.f);
  float ls0 = 0.f, ls1 = 0.f;
  #pragma unroll
  for (int pp = 0; pp < 2; ++pp)
    #pragma unroll
    for (int o = 0; o < 8; ++o) {
      const float e0 = __expf(lg2[pp][o][0] - M0);
      const float e1 = __expf(lg2[pp][o][1] - M1);
      lg2[pp][o] = (f32x2){e0, e1};
      ls0 += e0; ls1 += e1;
    }
  #pragma unroll
  for (int m = 1; m < 64; m <<= 1) {
    ls0 += __shfl_xor(ls0, m);
    ls1 += __shfl_xor(ls1, m);
  }
  const float eo0 = __expf(-M0), eo1 = __expf(-M1);
  const float iv0 = 1.f / (ls0 + (float)(Sk - width) * eo0);
  const float iv1 = 1.f / (ls1 + (float)(Sk - width) * eo1);
  const float fv0 = eo0 * iv0, fv1 = eo1 * iv1;

  const int t0 = (q0 >> 7) << 7;
  const int t127 = min(t0 + 127, S - 1);
  const int tLo = (max(bk[segq[max(t0 - 2, 0)]] - 4, 0)) & ~31;
  int tHi = min(bk[segq[min(t127 + 1, S - 1)] + 1] + 4, Sk);
  tHi = min((tHi + 31) & ~31, Sk);

  bfr* row0 = p + ((long long)(c0 + 0) * S + qa) * Sk;
  bfr* row1 = p + ((long long)(c0 + 1) * S + qa) * Sk;
  #pragma unroll
  for (int pp = 0; pp < 2; ++pp) {
    const int kk = loA + pp * 512 + lane * 8;
    if (kk + 7 < hiA) {
      u16x8 s0, s1;
      #pragma unroll
      for (int o = 0; o < 8; ++o) {
        s0[o] = f2bf(lg2[pp][o][0] * iv0 - fv0);
        s1[o] = f2bf(lg2[pp][o][1] * iv1 - fv1);
      }
      *(u16x8*)(row0 + kk) = s0;
      *(u16x8*)(row1 + kk) = s1;
    } else if (kk < hiA) {
      for (int o = 0; o < 8; ++o)
        if (kk + o < hiA) {
          row0[kk + o] = f2bf(lg2[pp][o][0] * iv0 - fv0);
          row1[kk + o] = f2bf(lg2[pp][o][1] * iv1 - fv1);
        }
    }
  }
  const u16x4 z4 = {0, 0, 0, 0};
  for (int k = tLo + lane * 4; k < loA; k += 256) {
    *(u16x4*)(row0 + k) = z4;
    *(u16x4*)(row1 + k) = z4;
  }
  for (int k = hiA + lane; k < tHi; k += 64) { row0[k] = 0; row1[k] = 0; }
  if (lane == 0) {
    fvArr[(long long)(h + 0) * S + qa] = fv0;
    fvArr[(long long)(h + 1) * S + qa] = fv1;
  }
}

// ---------------------------------------------------------------------------
// GroupNorm finalize + apply (reads bf16 outb).
// ---------------------------------------------------------------------------
__global__ void gn_finalize(const float* __restrict__ stats, float* __restrict__ mr, float invcnt)
{
  const int g = threadIdx.x;
  if (g < 16) {
    const float s = stats[2 * g], ss = stats[2 * g + 1];
    const float mu = s * invcnt;
    const float var = ss * invcnt - mu * mu;
    mr[2 * g] = mu;
    mr[2 * g + 1] = rsqrtf(var + 1e-5f);
  }
}

__global__ __launch_bounds__(256) void gn_apply(
    const bfr* __restrict__ outb, const float* __restrict__ mr,
    const float* __restrict__ gnw, const float* __restrict__ gnb,
    bfr* __restrict__ y, int S)
{
  const int h = blockIdx.y;
  const long long inner = ((long long)blockIdx.x * 256 + threadIdx.x) * 8;
  if (inner >= (long long)S * D_) return;
  const int s = (int)(inner >> 7), d = (int)(inner & 127);
  const int g = h >> 1;
  const float mu = mr[2 * g], rs = mr[2 * g + 1];
  const float wgt = gnw[h] * rs;
  const float b = gnb[h] - mu * wgt;
  const u16x8 v = *(const u16x8*)(outb + (long long)h * S * D_ + inner);
  u16x8 o;
  #pragma unroll
  for (int j = 0; j < 8; ++j) o[j] = f2bf(bf2f(v[j]) * wgt + b);
  *(u16x8*)(y + (long long)s * HID_ + h * D_ + d) = o;
}

// ---------------------------------------------------------------------------
// Launcher.
// ---------------------------------------------------------------------------
extern "C" void kernel_launch(void* const* d_in, const int* in_sizes, int n_in,
                              void* d_out, int out_size, void* d_ws, size_t ws_size,
                              hipStream_t stream)
{
  const float* x      = (const float*)d_in[0];
  const float* ctx    = (const float*)d_in[1];
  const float* wq     = (const float*)d_in[2];
  const float* wkv    = (const float*)d_in[3];
  const float* wo     = (const float*)d_in[4];
  const float* conv_w = (const float*)d_in[5];
  const float* gnw    = (const float*)d_in[6];
  const float* gnb    = (const float*)d_in[7];
  const void*  qsl    = d_in[8];
  const void*  ksl    = d_in[9];
  const int S    = in_sizes[0] / HID_;   // 1536
  const int Sk   = in_sizes[1] / HID_;   // 1536
  const int nseg = in_sizes[8];          // 4

  auto al = [](size_t v) { return (v + 255) & ~(size_t)255; };
  char* base = (char*)d_ws;
  size_t off = 0;
  auto take = [&](size_t bytes) -> char* { char* r = base + off; off += al(bytes); return r; };

  int*   segq  = (int*)take((size_t)S * 4);
  int*   segk  = (int*)take((size_t)Sk * 4);
  int*   bq    = (int*)take(64);
  int*   bk    = (int*)take(64);
  float* stats = (float*)take(128);
  float* mr    = (float*)take(128);
  float* fvArr = (float*)take((size_t)H_ * S * 4);
  float* csV   = (float*)take((size_t)H_ * D_ * 4);
  bfr*   qb    = (bfr*)take((size_t)H_ * S * D_ * 2);
  bfr*   kbuf  = (bfr*)take((size_t)H_ * Sk * D_ * 2);
  bfr*   vrow  = (bfr*)take((size_t)H_ * Sk * D_ * 2);
  bfr*   vt    = (bfr*)take((size_t)H_ * Sk * D_ * 2);
  bfr*   outb  = (bfr*)take((size_t)H_ * S * D_ * 2);   // bf16
  const size_t poolBase = off;
  char*  pool  = base + poolBase;

  const int Smax = (S > Sk) ? S : Sk;
  const size_t A1 = al((size_t)Smax * HID_ * 2);
  const size_t WT = al((size_t)HID_ * HID_ * 2);
  const size_t PART = al((size_t)2 * S * HID_ * 4);

  const size_t CAmin = al((size_t)4 * S * Sk * 2);
  const size_t fusedNeed = (A1 + 2 * WT > 2 * CAmin) ? (A1 + 2 * WT) : (2 * CAmin);
  const bool fused = (poolBase + fusedNeed <= ws_size);
  const bool splitOK = (poolBase + A1 + 2 * WT + PART <= ws_size);
  const size_t wNeed = A1 + (fused ? 2 : 1) * WT + (splitOK ? PART : 0);

  int nc = 4;
  {
    const int cands[3] = {32, 16, 8};
    for (int ci = 0; ci < 3; ++ci) {
      const size_t CA = al((size_t)cands[ci] * S * Sk * 2);
      const size_t need = (wNeed > 2 * CA) ? wNeed : (2 * CA);
      if (poolBase + need <= ws_size) { nc = cands[ci]; break; }
    }
  }
  const size_t CA = al((size_t)nc * S * Sk * 2);
  bfr*   xcb    = (bfr*)pool;
  bfr*   wT     = (bfr*)(pool + A1);
  float* partB  = (float*)(pool + A1 + 2 * WT);
  bfr*   attn_c = (bfr*)pool;
  bfr*   pbuf_c = (bfr*)(pool + CA);

  seg_setup<<<1, 256, 0, stream>>>(qsl, ksl, segq, segk, bq, bk, stats, S, Sk, nseg);

  GemmAux aux{};
  aux.segq = segq; aux.segk = segk; aux.bk = bk;
  aux.qb = qb; aux.kb = kbuf; aux.vrow = vrow;
  aux.outb = nullptr; aux.outb16 = outb; aux.stats = stats;
  aux.fvArr = fvArr; aux.colsum = csV;
  aux.scale = 0.08838834764831845f;  // 1/sqrt(128)
  aux.S = S; aux.Sk = Sk; aux.nOff = 0;

  const long long MN = (long long)S * HID_;
  const int nRed = (int)((MN / 8 + 255) / 256);

  // ---- Q projection ----
  const long long nx = (long long)S * HID_;
  cvt_bf16<<<(int)((nx / 8 + 255) / 256), 256, 0, stream>>>(x, xcb, nx);
  transpose_cvt<<<dim3(HID_ / 64, HID_ / 64), 256, 0, stream>>>(wq, wT, HID_, HID_);
  if (splitOK) {
    GemmAux auxQ = aux; auxQ.outb = partB;
    gemm_bt<MODE_Q, 2, 64><<<dim3(HID_ / 128, S / 128, 2), 256, 0, stream>>>(
        xcb, wT, nullptr, HID_, HID_, HID_, HID_, 0, 0, 0, auxQ);
    reduce_split_q<<<nRed, 256, 0, stream>>>(partB, qb, aux.scale, S);
  } else {
    gemm_bt<MODE_Q, 1, 64><<<dim3(HID_ / 128, S / 128, 1), 256, 0, stream>>>(
        xcb, wT, nullptr, HID_, HID_, HID_, HID_, 0, 0, 0, aux);
  }

  // ---- KV projection ----
  const long long nctx = (long long)Sk * HID_;
  cvt_bf16<<<(int)((nctx / 8 + 255) / 256), 256, 0, stream>>>(ctx, xcb, nctx);
  if (fused) {
    transpose_cvt<<<dim3(2 * HID_ / 64, HID_ / 64), 256, 0, stream>>>(wkv, wT, HID_, 2 * HID_);
    gemm_bt<MODE_KV, 1, 64><<<dim3(2 * HID_ / 128, Sk / 128, 1), 256, 0, stream>>>(
        xcb, wT, nullptr, 2 * HID_, HID_, HID_, HID_, 0, 0, 0, aux);
  } else {
    transpose_cvt<<<dim3(HID_ / 64, HID_ / 64), 256, 0, stream>>>(wkv, wT, HID_, 2 * HID_);
    gemm_bt<MODE_KV, 1, 64><<<dim3(HID_ / 128, Sk / 128, 1), 256, 0, stream>>>(
        xcb, wT, nullptr, HID_, HID_, HID_, HID_, 0, 0, 0, aux);
    transpose_cvt<<<dim3(HID_ / 64, HID_ / 64), 256, 0, stream>>>(wkv + HID_, wT, HID_, 2 * HID_);
    GemmAux auxV = aux; auxV.nOff = H_ * D_;
    gemm_bt<MODE_KV, 1, 64><<<dim3(HID_ / 128, Sk / 128, 1), 256, 0, stream>>>(
        xcb, wT, nullptr, HID_, HID_, HID_, HID_, 0, 0, 0, auxV);
  }

  // ---- V transpose + column sums ----
  transpose_b16<<<dim3(D_ / 64, Sk / 64, H_), 256, 0, stream>>>(vrow, vt, Sk, D_);
  colsum_v<<<H_ * D_ / 4, 256, 0, stream>>>(vt, csV, Sk);

  // ---- attention, chunked over heads ----
  for (int h0 = 0; h0 < H_; h0 += nc) {
    gemm_qk<<<dim3(Sk / 128, S / 128, nc), 256, 0, stream>>>(
        qb + (size_t)h0 * S * D_, kbuf + (size_t)h0 * Sk * D_, attn_c,
        (long long)S * D_, (long long)Sk * D_, (long long)S * Sk, aux);
    conv_softmax10<<<dim3(S / 4, nc / 2), 256, 0, stream>>>(
        attn_c, conv_w, pbuf_c, fvArr, segq, segk, bk, S, Sk, h0);
    GemmAux auxP = aux;
    auxP.outb16 = outb + (size_t)h0 * S * D_;
    auxP.stats = stats + h0;
    auxP.fvArr = fvArr + (size_t)h0 * S;
    auxP.colsum = csV + (size_t)h0 * D_;
    gemm_bt<MODE_PV, 1, 32><<<dim3(1, S / 128, nc), 256, 0, stream>>>(
        pbuf_c, vt + (size_t)h0 * D_ * Sk, nullptr,
        D_, Sk, Sk, Sk,
        (long long)S * Sk, (long long)D_ * Sk, 0, auxP);
  }

  // ---- GroupNorm + output projection ----
  gn_finalize<<<1, 32, 0, stream>>>(stats, mr, 1.0f / (2.0f * S * D_));
  gn_apply<<<dim3((S * D_) / 2048, H_), 256, 0, stream>>>(outb, mr, gnw, gnb, xcb, S);
  transpose_cvt<<<dim3(HID_ / 64, HID_ / 64), 256, 0, stream>>>(wo, wT, HID_, HID_);
  if (splitOK) {
    GemmAux auxO = aux; auxO.outb = partB;
    gemm_bt<MODE_PLAIN, 2, 64><<<dim3(HID_ / 128, S / 128, 2), 256, 0, stream>>>(
        xcb, wT, nullptr, HID_, HID_, HID_, HID_, 0, 0, 0, auxO);
    reduce_split_f32<<<nRed, 256, 0, stream>>>(partB, (float*)d_out, MN);
  } else {
    gemm_bt<MODE_PLAIN, 1, 64><<<dim3(HID_ / 128, S / 128, 1), 256, 0, stream>>>(
        xcb, wT, d_out, HID_, HID_, HID_, HID_, 0, 0, 0, aux);
  }
}